// Round 3
// baseline (287.551 us; speedup 1.0000x reference)
//
#include <hip/hip_runtime.h>
#include <hip/hip_bf16.h>

typedef unsigned short u16;
typedef unsigned int   u32;
typedef __attribute__((ext_vector_type(8))) short bf16x8;
typedef __attribute__((ext_vector_type(4))) float f32x4;

__device__ __forceinline__ u16 f2bf(float f) {
  u32 u = __float_as_uint(f);
  u32 r = u + 0x7fffu + ((u >> 16) & 1u);
  return (u16)(r >> 16);
}
__device__ __forceinline__ float bflo(u32 u) { return __uint_as_float(u << 16); }
__device__ __forceinline__ float bfhi(u32 u) { return __uint_as_float(u & 0xffff0000u); }
// pack (hi16(b)<<16)|hi16(a) in one v_perm (truncation-to-bf16; bias cancels
// in softmax normalization, ~0.4% rel elsewhere — noise vs 0.109 threshold)
__device__ __forceinline__ u32 packhi(float a, float b) {
  return __builtin_amdgcn_perm(__float_as_uint(b), __float_as_uint(a), 0x07060302u);
}

// ---------------------------------------------------------------------------
// Kernel 1: avgpool 2x2 + Q/K/V 1x1-conv projections via MFMA.
// grid 1024 x 256 (4 waves). side = blockIdx&1 (0: rgb->Q, 1: freq->K,V).
// Q,K stored [b][n][64] bf16; V stored [b][64][n] bf16.
// Q pre-scaled by hid^-0.5 * log2(e) = 0.125*1.4426950 so k_attn can use
// exp2 directly (saves one v_mul per softmax element).
// ---------------------------------------------------------------------------
__global__ __launch_bounds__(256, 4) void k_qkv(
    const float* __restrict__ rgb, const float* __restrict__ freq,
    const float* __restrict__ wq, const float* __restrict__ bq,
    const float* __restrict__ wk, const float* __restrict__ bk,
    const float* __restrict__ wv, const float* __restrict__ bv,
    u16* __restrict__ Qo, u16* __restrict__ Ko, u16* __restrict__ Vo)
{
  __shared__ __align__(16) u16 sm[3 * 4608];
  u16* X  = sm;             // [64][72] pooled input tokens
  u16* W0 = sm + 4608;      // [64][72] wq or wk
  u16* W1 = sm + 9216;      // [64][72] wv (side 1 only)

  const int t    = threadIdx.x;
  const int side = blockIdx.x & 1;
  const int seg  = blockIdx.x >> 1;       // 0..511
  const int idx0 = seg * 64;              // global token base (b*4096+n)
  const int bb   = idx0 >> 12;
  const int n0   = idx0 & 4095;
  const int h    = n0 >> 6;               // pooled row (uniform per block)
  const float* src = side ? freq : rgb;

  // ---- stage pooled X: 64 tokens (one pooled row) x 64 ch ----
  const size_t sbase = (size_t)bb * 64 * 16384 + (size_t)(2 * h) * 128;
  for (int i = 0; i < 2; ++i) {
    int cell = i * 256 + t;               // 0..511
    int tok  = cell & 63;                 // lane-consecutive -> coalesced
    int grp  = cell >> 6;                 // channel granule 0..7
    const float* p0 = src + sbase + 2 * tok + (size_t)(grp * 8) * 16384;
    u32 pk[4];
#pragma unroll
    for (int cc = 0; cc < 8; cc += 2) {
      const float* pa = p0 + (size_t)cc * 16384;
      float2 a0 = *(const float2*)pa;
      float2 a1 = *(const float2*)(pa + 128);
      float v0 = 0.25f * ((a0.x + a0.y) + (a1.x + a1.y));
      const float* pb = pa + 16384;
      float2 b0 = *(const float2*)pb;
      float2 b1 = *(const float2*)(pb + 128);
      float v1 = 0.25f * ((b0.x + b0.y) + (b1.x + b1.y));
      pk[cc >> 1] = (u32)f2bf(v0) | ((u32)f2bf(v1) << 16);
    }
    uint4 q4; q4.x = pk[0]; q4.y = pk[1]; q4.z = pk[2]; q4.w = pk[3];
    *(uint4*)&X[tok * 72 + grp * 8] = q4;
  }
  // ---- stage weights, float4-coalesced: thread -> (o = t>>2, c0 = (t&3)*16)
  {
    const int o = t >> 2, c0 = (t & 3) << 4;
    const float4* p4 = (const float4*)((side ? wk : wq) + o * 64 + c0);
    float4 f0 = p4[0], f1 = p4[1], f2 = p4[2], f3 = p4[3];
    uint4 qa, qb;
    qa.x = (u32)f2bf(f0.x) | ((u32)f2bf(f0.y) << 16);
    qa.y = (u32)f2bf(f0.z) | ((u32)f2bf(f0.w) << 16);
    qa.z = (u32)f2bf(f1.x) | ((u32)f2bf(f1.y) << 16);
    qa.w = (u32)f2bf(f1.z) | ((u32)f2bf(f1.w) << 16);
    qb.x = (u32)f2bf(f2.x) | ((u32)f2bf(f2.y) << 16);
    qb.y = (u32)f2bf(f2.z) | ((u32)f2bf(f2.w) << 16);
    qb.z = (u32)f2bf(f3.x) | ((u32)f2bf(f3.y) << 16);
    qb.w = (u32)f2bf(f3.z) | ((u32)f2bf(f3.w) << 16);
    *(uint4*)&W0[o * 72 + c0] = qa;
    *(uint4*)&W0[o * 72 + c0 + 8] = qb;
    if (side) {
      const float4* v4 = (const float4*)(wv + o * 64 + c0);
      float4 g0 = v4[0], g1 = v4[1], g2 = v4[2], g3 = v4[3];
      qa.x = (u32)f2bf(g0.x) | ((u32)f2bf(g0.y) << 16);
      qa.y = (u32)f2bf(g0.z) | ((u32)f2bf(g0.w) << 16);
      qa.z = (u32)f2bf(g1.x) | ((u32)f2bf(g1.y) << 16);
      qa.w = (u32)f2bf(g1.z) | ((u32)f2bf(g1.w) << 16);
      qb.x = (u32)f2bf(g2.x) | ((u32)f2bf(g2.y) << 16);
      qb.y = (u32)f2bf(g2.z) | ((u32)f2bf(g2.w) << 16);
      qb.z = (u32)f2bf(g3.x) | ((u32)f2bf(g3.y) << 16);
      qb.w = (u32)f2bf(g3.z) | ((u32)f2bf(g3.w) << 16);
      *(uint4*)&W1[o * 72 + c0] = qa;
      *(uint4*)&W1[o * 72 + c0 + 8] = qb;
    }
  }
  __syncthreads();

  const int lane = t & 63, w = t >> 6;
  const int l15 = lane & 15, qd = lane >> 4;
  const int tb = w * 16;                  // wave's 16 tokens

  bf16x8 af0 = *(const bf16x8*)&X[(tb + l15) * 72 + qd * 8];
  bf16x8 af1 = *(const bf16x8*)&X[(tb + l15) * 72 + 32 + qd * 8];

  // ---- Q (side 0) / K (side 1): A = X (rows tok), B = W0 (cols o) ----
  f32x4 acc[4];
#pragma unroll
  for (int nt = 0; nt < 4; ++nt) {
    bf16x8 b0 = *(const bf16x8*)&W0[(nt * 16 + l15) * 72 + qd * 8];
    bf16x8 b1 = *(const bf16x8*)&W0[(nt * 16 + l15) * 72 + 32 + qd * 8];
    f32x4 a = {0.f, 0.f, 0.f, 0.f};
    a = __builtin_amdgcn_mfma_f32_16x16x32_bf16(af0, b0, a, 0, 0, 0);
    a = __builtin_amdgcn_mfma_f32_16x16x32_bf16(af1, b1, a, 0, 0, 0);
    acc[nt] = a;
  }
  {
    const float* bias0 = side ? bk : bq;
    // Q scale = hid^-0.5 * log2(e); K unscaled
    const float sc = side ? 1.f : 0.18033688f;
    u16* dst0 = side ? Ko : Qo;
#pragma unroll
    for (int nt = 0; nt < 4; ++nt) {
      float bia = bias0[nt * 16 + l15];
#pragma unroll
      for (int e = 0; e < 4; ++e) {
        int tok = idx0 + tb + qd * 4 + e;     // D row = token
        dst0[(size_t)tok * 64 + nt * 16 + l15] = f2bf((acc[nt][e] + bia) * sc);
      }
    }
  }

  if (side) {
    // ---- V: A = Wv (rows c), B = X (cols tok) -> D = V^T directly ----
    f32x4 accv[4];
#pragma unroll
    for (int ct = 0; ct < 4; ++ct) {
      bf16x8 a0 = *(const bf16x8*)&W1[(ct * 16 + l15) * 72 + qd * 8];
      bf16x8 a1 = *(const bf16x8*)&W1[(ct * 16 + l15) * 72 + 32 + qd * 8];
      f32x4 a = {0.f, 0.f, 0.f, 0.f};
      a = __builtin_amdgcn_mfma_f32_16x16x32_bf16(a0, af0, a, 0, 0, 0);
      a = __builtin_amdgcn_mfma_f32_16x16x32_bf16(a1, af1, a, 0, 0, 0);
      accv[ct] = a;
    }
#pragma unroll
    for (int ct = 0; ct < 4; ++ct) {
#pragma unroll
      for (int e = 0; e < 4; ++e) {
        int c = ct * 16 + qd * 4 + e;          // D row = V channel
        float v = accv[ct][e] + bv[c];
        Vo[((size_t)(bb * 64 + c)) * 4096 + n0 + tb + l15] = f2bf(v);
      }
    }
  }
}

// ---------------------------------------------------------------------------
// Kernel 2: attention + fused output-conv/BN epilogue, barrier-free K-loop.
// grid (8 b, 64 qtile) x 512 threads = 8 independent waves.
// Occupancy was the round-0 bottleneck (2 waves/SIMD, ~60% dual-pipe idle =
// exposed L2 latency; the register double-buffer fix spilled at the 128-VGPR
// arch cap). Structural fix: same grid, 512-thread blocks -> 16 waves/CU =
// 4 waves/SIMD, with per-wave register demand ~112 (fits 128, no spill).
// Wave w: q-half qh=w>>2 (32 q rows), key-split ks=w&3 (keys ks*1024..+1024,
// 16 tiles of 64). The (qh=0,ks)/(qh=1,ks) wave pair walks the same K/V tile
// sequence -> second reader mostly L1/L2-hits.
// No-max softmax (exp2; log2e folded into Q scale); partials combine
// additively. Epilogue: combine 8 partials + normalize Z in LDS (bf16), then
// Y = BNaffine(Wo·Z) via MFMA, store Ya[b][n][64] bf16. Conv/BN commute with
// the bilinear resize — LeakyReLU applied post-interp in k_out.
// ---------------------------------------------------------------------------
__global__ __launch_bounds__(512, 4) void k_attn(
    const u16* __restrict__ Qg, const u16* __restrict__ Kg,
    const u16* __restrict__ Vg,
    const float* __restrict__ wo, const float* __restrict__ bo,
    const float* __restrict__ gam, const float* __restrict__ bet,
    const float* __restrict__ mean, const float* __restrict__ var,
    u16* __restrict__ Ya)
{
  __shared__ __align__(16) u16 Pb[8 * 2304];   // per-wave [32 q][72] P / partial-Z
  __shared__ __align__(16) u16 Wl[4608];       // Wo [64 o][72]
  __shared__ __align__(16) u16 Zc[4608];       // combined Z [64 q][72]
  __shared__ float lb[256];                    // [wave][32 q] denominators

  const int b  = blockIdx.x;                   // batch -> XCD affinity
  const int q0 = blockIdx.y * 64;
  const int t  = threadIdx.x;
  const int lane = t & 63, w = t >> 6;         // w = 0..7
  const int qh = w >> 2, ks = w & 3;
  const int l15 = lane & 15, qd = lane >> 4;
  u16* P = Pb + w * 2304;

  // ---- stage Wo (bf16, rounded): 512 thr -> (o = t>>3, c0 = (t&7)*8) ----
  {
    const int o = t >> 3, c0 = (t & 7) << 3;
    const float4* p4 = (const float4*)(wo + o * 64 + c0);
    float4 f0 = p4[0], f1 = p4[1];
    uint4 qa;
    qa.x = (u32)f2bf(f0.x) | ((u32)f2bf(f0.y) << 16);
    qa.y = (u32)f2bf(f0.z) | ((u32)f2bf(f0.w) << 16);
    qa.z = (u32)f2bf(f1.x) | ((u32)f2bf(f1.y) << 16);
    qa.w = (u32)f2bf(f1.z) | ((u32)f2bf(f1.w) << 16);
    *(uint4*)&Wl[o * 72 + c0] = qa;
  }

  // ---- Q fragments (B-operand, scale*log2e pre-folded): 2 q-tiles ----
  bf16x8 qf[2][2];
#pragma unroll
  for (int qt = 0; qt < 2; ++qt) {
    const u16* p = Qg + ((size_t)(b * 4096 + q0 + qh * 32 + qt * 16 + l15)) * 64 + qd * 8;
    qf[qt][0] = *(const bf16x8*)p;
    qf[qt][1] = *(const bf16x8*)(p + 32);
  }

  f32x4 zacc[4][2];                            // [ct][qt]
#pragma unroll
  for (int i = 0; i < 4; ++i)
#pragma unroll
    for (int j = 0; j < 2; ++j) {
      f32x4 z = {0.f, 0.f, 0.f, 0.f};
      zacc[i][j] = z;
    }
  float lacc[2] = {0.f, 0.f};

  for (int tile = 0; tile < 16; ++tile) {
    const int nn = ks * 1024 + tile * 64;

    // K tile loads first (QK stalls only on these; V issued after last kf use)
    bf16x8 kf[4][2];
#pragma unroll
    for (int mt = 0; mt < 4; ++mt) {
      const u16* p = Kg + ((size_t)(b * 4096 + nn + mt * 16 + l15)) * 64 + qd * 8;
      kf[mt][0] = *(const bf16x8*)p;
      kf[mt][1] = *(const bf16x8*)(p + 32);
    }

    // ---- S^T = K·Q^T, exp2, pack P[q][key] (perm-truncated bf16) ----
#pragma unroll
    for (int qt = 0; qt < 2; ++qt) {
#pragma unroll
      for (int mt = 0; mt < 4; ++mt) {
        f32x4 a = {0.f, 0.f, 0.f, 0.f};
        a = __builtin_amdgcn_mfma_f32_16x16x32_bf16(kf[mt][0], qf[qt][0], a, 0, 0, 0);
        a = __builtin_amdgcn_mfma_f32_16x16x32_bf16(kf[mt][1], qf[qt][1], a, 0, 0, 0);
        float p0 = __builtin_amdgcn_exp2f(a[0]);
        float p1 = __builtin_amdgcn_exp2f(a[1]);
        float p2 = __builtin_amdgcn_exp2f(a[2]);
        float p3 = __builtin_amdgcn_exp2f(a[3]);
        lacc[qt] += (p0 + p1) + (p2 + p3);
        uint2 pw;
        pw.x = packhi(p0, p1);
        pw.y = packhi(p2, p3);
        *(uint2*)&P[(qt * 16 + l15) * 72 + mt * 16 + qd * 4] = pw;
      }
    }

    // V tile loads (latency hidden under exp/pack + other 3 waves/SIMD)
    bf16x8 vf[4][2];
#pragma unroll
    for (int ct = 0; ct < 4; ++ct) {
      const u16* p = Vg + ((size_t)(b * 64 + ct * 16 + l15)) * 4096 + nn + qd * 8;
      vf[ct][0] = *(const bf16x8*)p;
      vf[ct][1] = *(const bf16x8*)(p + 32);
    }

    // ---- Z^T += V^T · P^T ----
#pragma unroll
    for (int qt = 0; qt < 2; ++qt) {
      bf16x8 pf0 = *(const bf16x8*)&P[(qt * 16 + l15) * 72 + qd * 8];
      bf16x8 pf1 = *(const bf16x8*)&P[(qt * 16 + l15) * 72 + 32 + qd * 8];
#pragma unroll
      for (int ct = 0; ct < 4; ++ct) {
        zacc[ct][qt] = __builtin_amdgcn_mfma_f32_16x16x32_bf16(vf[ct][0], pf0, zacc[ct][qt], 0, 0, 0);
        zacc[ct][qt] = __builtin_amdgcn_mfma_f32_16x16x32_bf16(vf[ct][1], pf1, zacc[ct][qt], 0, 0, 0);
      }
    }
  }

  // ---- epilogue: denominators + unnormalized partial Z ([q][c] bf16) ----
#pragma unroll
  for (int qt = 0; qt < 2; ++qt) {
    float l = lacc[qt];
    l += __shfl_xor(l, 16);
    l += __shfl_xor(l, 32);
    lb[w * 32 + qt * 16 + l15] = l;   // all quads write same value: benign
  }
#pragma unroll
  for (int qt = 0; qt < 2; ++qt)
#pragma unroll
    for (int ct = 0; ct < 4; ++ct) {
      uint2 pw;
      pw.x = packhi(zacc[ct][qt][0], zacc[ct][qt][1]);
      pw.y = packhi(zacc[ct][qt][2], zacc[ct][qt][3]);
      *(uint2*)&P[(qt * 16 + l15) * 72 + ct * 16 + qd * 4] = pw;
    }
  __syncthreads();

  // ---- combine 8 partials (2 qh x 4 ks) + normalize -> Zc[q][72] bf16 ----
  {
    const u32* Pu = (const u32*)Pb;            // wave stride 1152 u32, row 36
    u32* Zu = (u32*)Zc;
#pragma unroll
    for (int i = 0; i < 4; ++i) {
      int cell = i * 512 + t;                  // 0..2047
      int q = cell >> 5, cu = cell & 31;       // q 0..63, u32 col 0..31
      int qh2 = q >> 5, qq = q & 31;
      float s0 = 0.f, s1 = 0.f;
      float den = 0.f;
#pragma unroll
      for (int ww = 0; ww < 4; ++ww) {
        u32 v = Pu[(qh2 * 4 + ww) * 1152 + qq * 36 + cu];
        s0 += bflo(v);
        s1 += bfhi(v);
        den += lb[(qh2 * 4 + ww) * 32 + qq];
      }
      float inv = 1.f / den;
      Zu[q * 36 + cu] = packhi(s0 * inv, s1 * inv);
    }
  }
  __syncthreads();

  // ---- Y = affine(Wo · Z): wave w -> q rows (w&3)*16..+15, o-half w>>2 ----
  {
    const int qr = w & 3, oh = w >> 2;
    bf16x8 af0 = *(const bf16x8*)&Zc[(qr * 16 + l15) * 72 + qd * 8];
    bf16x8 af1 = *(const bf16x8*)&Zc[(qr * 16 + l15) * 72 + 32 + qd * 8];
#pragma unroll
    for (int ni = 0; ni < 2; ++ni) {
      const int nt = oh * 2 + ni;
      bf16x8 b0 = *(const bf16x8*)&Wl[(nt * 16 + l15) * 72 + qd * 8];
      bf16x8 b1 = *(const bf16x8*)&Wl[(nt * 16 + l15) * 72 + 32 + qd * 8];
      f32x4 y = {0.f, 0.f, 0.f, 0.f};
      y = __builtin_amdgcn_mfma_f32_16x16x32_bf16(af0, b0, y, 0, 0, 0);
      y = __builtin_amdgcn_mfma_f32_16x16x32_bf16(af1, b1, y, 0, 0, 0);
      const int o = nt * 16 + l15;
      float A = gam[o] * __frsqrt_rn(var[o] + 1e-5f);
      float B = (bo[o] - mean[o]) * A + bet[o];
#pragma unroll
      for (int e = 0; e < 4; ++e) {
        float v = y[e] * A + B;
        size_t tok = (size_t)(b * 4096 + q0 + qr * 16 + qd * 4 + e);
        Ya[tok * 64 + o] = (u16)(__float_as_uint(v) >> 16);
      }
    }
  }
}

// ---------------------------------------------------------------------------
// Kernel 3: bilinear 2x upsample of Ya + LeakyReLU + residual.
// grid 512 x 256: thread = one (b,i,j) output pixel, all 64 channels.
// Ya is channel-innermost -> 4 corners are contiguous 128 B bf16 runs.
// ---------------------------------------------------------------------------
__global__ __launch_bounds__(256, 4) void k_out(
    const u16* __restrict__ Ya, const float* __restrict__ rgb,
    float* __restrict__ out)
{
  const int px = blockIdx.x * 256 + threadIdx.x;   // 0..131071
  const int j = px & 127;
  const int i = (px >> 7) & 127;
  const int b = px >> 14;

  float ys = fmaxf((i + 0.5f) * 0.5f - 0.5f, 0.f);
  int   y0 = (int)ys;
  float wy = ys - (float)y0;
  int   y1 = min(y0 + 1, 63);
  float xs = fmaxf((j + 0.5f) * 0.5f - 0.5f, 0.f);
  int   x0 = (int)xs;
  float wx = xs - (float)x0;
  int   x1 = min(x0 + 1, 63);
  float w00 = (1.f - wy) * (1.f - wx), w01 = (1.f - wy) * wx;
  float w10 = wy * (1.f - wx),         w11 = wy * wx;

  const u16* yb = Ya + (size_t)b * 262144;
  const int b00 = (y0 * 64 + x0) * 64, b01 = (y0 * 64 + x1) * 64;
  const int b10 = (y1 * 64 + x0) * 64, b11 = (y1 * 64 + x1) * 64;

#pragma unroll
  for (int ch = 0; ch < 8; ++ch) {
    uint4 a00 = *(const uint4*)&yb[b00 + ch * 8];
    uint4 a01 = *(const uint4*)&yb[b01 + ch * 8];
    uint4 a10 = *(const uint4*)&yb[b10 + ch * 8];
    uint4 a11 = *(const uint4*)&yb[b11 + ch * 8];
    const u32* u00 = (const u32*)&a00;
    const u32* u01 = (const u32*)&a01;
    const u32* u10 = (const u32*)&a10;
    const u32* u11 = (const u32*)&a11;
#pragma unroll
    for (int e = 0; e < 8; ++e) {
      const int wd = e >> 1;
      float c00 = (e & 1) ? bfhi(u00[wd]) : bflo(u00[wd]);
      float c01 = (e & 1) ? bfhi(u01[wd]) : bflo(u01[wd]);
      float c10 = (e & 1) ? bfhi(u10[wd]) : bflo(u10[wd]);
      float c11 = (e & 1) ? bfhi(u11[wd]) : bflo(u11[wd]);
      float v = w00 * c00 + w01 * c01 + w10 * c10 + w11 * c11;
      v = (v >= 0.f) ? v : 0.2f * v;
      const int o = ch * 8 + e;
      const size_t oi = ((size_t)((b * 64 + o) * 128 + i)) * 128 + j;
      out[oi] = rgb[oi] + v;
    }
  }
}

// ---------------------------------------------------------------------------
extern "C" void kernel_launch(void* const* d_in, const int* in_sizes, int n_in,
                              void* d_out, int out_size, void* d_ws, size_t ws_size,
                              hipStream_t stream) {
  (void)in_sizes; (void)n_in; (void)out_size; (void)ws_size;
  const float* rgb  = (const float*)d_in[0];
  const float* freq = (const float*)d_in[1];
  const float* wq   = (const float*)d_in[2];
  const float* bq   = (const float*)d_in[3];
  const float* wk   = (const float*)d_in[4];
  const float* bk   = (const float*)d_in[5];
  const float* wv   = (const float*)d_in[6];
  const float* bv   = (const float*)d_in[7];
  const float* wo   = (const float*)d_in[8];
  const float* bo   = (const float*)d_in[9];
  const float* gam  = (const float*)d_in[10];
  const float* bet  = (const float*)d_in[11];
  const float* mean = (const float*)d_in[12];
  const float* var  = (const float*)d_in[13];

  char* ws = (char*)d_ws;
  u16* Qw = (u16*)(ws);               // 8*4096*64 bf16 = 4 MiB
  u16* Kw = (u16*)(ws + 4194304);     // 4 MiB
  u16* Vw = (u16*)(ws + 8388608);     // 4 MiB (transposed [b][c][n])
  u16* Yw = (u16*)(ws + 12582912);    // 4 MiB  Ya[b][n][64] bf16

  k_qkv<<<dim3(1024), dim3(256), 0, stream>>>(rgb, freq, wq, bq, wk, bk, wv, bv,
                                              Qw, Kw, Vw);
  k_attn<<<dim3(8, 64), dim3(512), 0, stream>>>(Qw, Kw, Vw, wo, bo, gam, bet,
                                                mean, var, Yw);
  k_out<<<dim3(512), dim3(256), 0, stream>>>(Yw, rgb, (float*)d_out);
}

// Round 4
// 264.669 us; speedup vs baseline: 1.0865x; 1.0865x over previous
//
#include <hip/hip_runtime.h>
#include <hip/hip_bf16.h>

typedef unsigned short u16;
typedef unsigned int   u32;
typedef __attribute__((ext_vector_type(8))) short bf16x8;
typedef __attribute__((ext_vector_type(4))) float f32x4;

__device__ __forceinline__ u16 f2bf(float f) {
  u32 u = __float_as_uint(f);
  u32 r = u + 0x7fffu + ((u >> 16) & 1u);
  return (u16)(r >> 16);
}
__device__ __forceinline__ float bflo(u32 u) { return __uint_as_float(u << 16); }
__device__ __forceinline__ float bfhi(u32 u) { return __uint_as_float(u & 0xffff0000u); }
// pack (hi16(b)<<16)|hi16(a) in one v_perm (truncation-to-bf16; bias cancels
// in softmax normalization, ~0.4% rel elsewhere — noise vs 0.109 threshold)
__device__ __forceinline__ u32 packhi(float a, float b) {
  return __builtin_amdgcn_perm(__float_as_uint(b), __float_as_uint(a), 0x07060302u);
}

// ---------------------------------------------------------------------------
// Kernel 1: avgpool 2x2 + Q/K/V 1x1-conv projections via MFMA.
// grid 1024 x 256 (4 waves). side = blockIdx&1 (0: rgb->Q, 1: freq->K,V).
// Q,K stored [b][n][64] bf16; V stored [b][64][n] bf16.
// Q pre-scaled by hid^-0.5 * log2(e) = 0.125*1.4426950 so k_attn can use
// exp2 directly (saves one v_mul per softmax element).
// ---------------------------------------------------------------------------
__global__ __launch_bounds__(256, 4) void k_qkv(
    const float* __restrict__ rgb, const float* __restrict__ freq,
    const float* __restrict__ wq, const float* __restrict__ bq,
    const float* __restrict__ wk, const float* __restrict__ bk,
    const float* __restrict__ wv, const float* __restrict__ bv,
    u16* __restrict__ Qo, u16* __restrict__ Ko, u16* __restrict__ Vo)
{
  __shared__ __align__(16) u16 sm[3 * 4608];
  u16* X  = sm;             // [64][72] pooled input tokens
  u16* W0 = sm + 4608;      // [64][72] wq or wk
  u16* W1 = sm + 9216;      // [64][72] wv (side 1 only)

  const int t    = threadIdx.x;
  const int side = blockIdx.x & 1;
  const int seg  = blockIdx.x >> 1;       // 0..511
  const int idx0 = seg * 64;              // global token base (b*4096+n)
  const int bb   = idx0 >> 12;
  const int n0   = idx0 & 4095;
  const int h    = n0 >> 6;               // pooled row (uniform per block)
  const float* src = side ? freq : rgb;

  // ---- stage pooled X: 64 tokens (one pooled row) x 64 ch ----
  const size_t sbase = (size_t)bb * 64 * 16384 + (size_t)(2 * h) * 128;
  for (int i = 0; i < 2; ++i) {
    int cell = i * 256 + t;               // 0..511
    int tok  = cell & 63;                 // lane-consecutive -> coalesced
    int grp  = cell >> 6;                 // channel granule 0..7
    const float* p0 = src + sbase + 2 * tok + (size_t)(grp * 8) * 16384;
    u32 pk[4];
#pragma unroll
    for (int cc = 0; cc < 8; cc += 2) {
      const float* pa = p0 + (size_t)cc * 16384;
      float2 a0 = *(const float2*)pa;
      float2 a1 = *(const float2*)(pa + 128);
      float v0 = 0.25f * ((a0.x + a0.y) + (a1.x + a1.y));
      const float* pb = pa + 16384;
      float2 b0 = *(const float2*)pb;
      float2 b1 = *(const float2*)(pb + 128);
      float v1 = 0.25f * ((b0.x + b0.y) + (b1.x + b1.y));
      pk[cc >> 1] = (u32)f2bf(v0) | ((u32)f2bf(v1) << 16);
    }
    uint4 q4; q4.x = pk[0]; q4.y = pk[1]; q4.z = pk[2]; q4.w = pk[3];
    *(uint4*)&X[tok * 72 + grp * 8] = q4;
  }
  // ---- stage weights, float4-coalesced: thread -> (o = t>>2, c0 = (t&3)*16)
  {
    const int o = t >> 2, c0 = (t & 3) << 4;
    const float4* p4 = (const float4*)((side ? wk : wq) + o * 64 + c0);
    float4 f0 = p4[0], f1 = p4[1], f2 = p4[2], f3 = p4[3];
    uint4 qa, qb;
    qa.x = (u32)f2bf(f0.x) | ((u32)f2bf(f0.y) << 16);
    qa.y = (u32)f2bf(f0.z) | ((u32)f2bf(f0.w) << 16);
    qa.z = (u32)f2bf(f1.x) | ((u32)f2bf(f1.y) << 16);
    qa.w = (u32)f2bf(f1.z) | ((u32)f2bf(f1.w) << 16);
    qb.x = (u32)f2bf(f2.x) | ((u32)f2bf(f2.y) << 16);
    qb.y = (u32)f2bf(f2.z) | ((u32)f2bf(f2.w) << 16);
    qb.z = (u32)f2bf(f3.x) | ((u32)f2bf(f3.y) << 16);
    qb.w = (u32)f2bf(f3.z) | ((u32)f2bf(f3.w) << 16);
    *(uint4*)&W0[o * 72 + c0] = qa;
    *(uint4*)&W0[o * 72 + c0 + 8] = qb;
    if (side) {
      const float4* v4 = (const float4*)(wv + o * 64 + c0);
      float4 g0 = v4[0], g1 = v4[1], g2 = v4[2], g3 = v4[3];
      qa.x = (u32)f2bf(g0.x) | ((u32)f2bf(g0.y) << 16);
      qa.y = (u32)f2bf(g0.z) | ((u32)f2bf(g0.w) << 16);
      qa.z = (u32)f2bf(g1.x) | ((u32)f2bf(g1.y) << 16);
      qa.w = (u32)f2bf(g1.z) | ((u32)f2bf(g1.w) << 16);
      qb.x = (u32)f2bf(g2.x) | ((u32)f2bf(g2.y) << 16);
      qb.y = (u32)f2bf(g2.z) | ((u32)f2bf(g2.w) << 16);
      qb.z = (u32)f2bf(g3.x) | ((u32)f2bf(g3.y) << 16);
      qb.w = (u32)f2bf(g3.z) | ((u32)f2bf(g3.w) << 16);
      *(uint4*)&W1[o * 72 + c0] = qa;
      *(uint4*)&W1[o * 72 + c0 + 8] = qb;
    }
  }
  __syncthreads();

  const int lane = t & 63, w = t >> 6;
  const int l15 = lane & 15, qd = lane >> 4;
  const int tb = w * 16;                  // wave's 16 tokens

  bf16x8 af0 = *(const bf16x8*)&X[(tb + l15) * 72 + qd * 8];
  bf16x8 af1 = *(const bf16x8*)&X[(tb + l15) * 72 + 32 + qd * 8];

  // ---- Q (side 0) / K (side 1): A = X (rows tok), B = W0 (cols o) ----
  f32x4 acc[4];
#pragma unroll
  for (int nt = 0; nt < 4; ++nt) {
    bf16x8 b0 = *(const bf16x8*)&W0[(nt * 16 + l15) * 72 + qd * 8];
    bf16x8 b1 = *(const bf16x8*)&W0[(nt * 16 + l15) * 72 + 32 + qd * 8];
    f32x4 a = {0.f, 0.f, 0.f, 0.f};
    a = __builtin_amdgcn_mfma_f32_16x16x32_bf16(af0, b0, a, 0, 0, 0);
    a = __builtin_amdgcn_mfma_f32_16x16x32_bf16(af1, b1, a, 0, 0, 0);
    acc[nt] = a;
  }
  {
    const float* bias0 = side ? bk : bq;
    // Q scale = hid^-0.5 * log2(e); K unscaled
    const float sc = side ? 1.f : 0.18033688f;
    u16* dst0 = side ? Ko : Qo;
#pragma unroll
    for (int nt = 0; nt < 4; ++nt) {
      float bia = bias0[nt * 16 + l15];
#pragma unroll
      for (int e = 0; e < 4; ++e) {
        int tok = idx0 + tb + qd * 4 + e;     // D row = token
        dst0[(size_t)tok * 64 + nt * 16 + l15] = f2bf((acc[nt][e] + bia) * sc);
      }
    }
  }

  if (side) {
    // ---- V: A = Wv (rows c), B = X (cols tok) -> D = V^T directly ----
    f32x4 accv[4];
#pragma unroll
    for (int ct = 0; ct < 4; ++ct) {
      bf16x8 a0 = *(const bf16x8*)&W1[(ct * 16 + l15) * 72 + qd * 8];
      bf16x8 a1 = *(const bf16x8*)&W1[(ct * 16 + l15) * 72 + 32 + qd * 8];
      f32x4 a = {0.f, 0.f, 0.f, 0.f};
      a = __builtin_amdgcn_mfma_f32_16x16x32_bf16(a0, af0, a, 0, 0, 0);
      a = __builtin_amdgcn_mfma_f32_16x16x32_bf16(a1, af1, a, 0, 0, 0);
      accv[ct] = a;
    }
#pragma unroll
    for (int ct = 0; ct < 4; ++ct) {
#pragma unroll
      for (int e = 0; e < 4; ++e) {
        int c = ct * 16 + qd * 4 + e;          // D row = V channel
        float v = accv[ct][e] + bv[c];
        Vo[((size_t)(bb * 64 + c)) * 4096 + n0 + tb + l15] = f2bf(v);
      }
    }
  }
}

// ---------------------------------------------------------------------------
// Kernel 2: attention + fused output-conv/BN epilogue, barrier-free K-loop.
// grid (8 b, 128 qtile) x 256 threads = 4 independent waves.
// Occupancy history: 2 waves/SIMD (r0, 74us, 60% dual-pipe idle) -> 512-thr
// blocks hit the hipcc allocator pathology (cap 64 VGPR, spilled, r3).
// Fix: 32-q blocks on a 2x grid -> 4 blocks/CU x 4 waves = 4 waves/SIMD,
// 256-thr blocks with launch_bounds(256,4) = the proven 128-VGPR regime.
// Wave w = key-split w (keys w*1024..+1024, 16 tiles of 64), all 32 block-q.
// K,V frags direct from global (L2-resident per XCD: 1 MB/batch).
// No-max softmax (exp2; log2e folded into Q scale); partials combine
// additively. Epilogue: combine 4 partials + normalize Z in LDS (bf16), then
// Y = BNaffine(Wo·Z) via MFMA, store Ya[b][n][64] bf16. Conv/BN commute with
// the bilinear resize — LeakyReLU applied post-interp in k_out.
// ---------------------------------------------------------------------------
__global__ __launch_bounds__(256, 4) void k_attn(
    const u16* __restrict__ Qg, const u16* __restrict__ Kg,
    const u16* __restrict__ Vg,
    const float* __restrict__ wo, const float* __restrict__ bo,
    const float* __restrict__ gam, const float* __restrict__ bet,
    const float* __restrict__ mean, const float* __restrict__ var,
    u16* __restrict__ Ya)
{
  __shared__ __align__(16) u16 Pb[4 * 2304];   // per-wave [32 q][72] P / partial-Z
  __shared__ __align__(16) u16 Wl[4608];       // Wo [64 o][72]
  __shared__ __align__(16) u16 Zc[2304];       // combined Z [32 q][72]
  __shared__ float lb[128];                    // [wave][32 q] denominators

  const int b  = blockIdx.x;                   // batch -> XCD affinity
  const int q0 = blockIdx.y * 32;
  const int t  = threadIdx.x;
  const int lane = t & 63, w = t >> 6;         // w = key-split 0..3
  const int l15 = lane & 15, qd = lane >> 4;
  u16* P = Pb + w * 2304;

  // ---- stage Wo (bf16, rounded) for the epilogue GEMM ----
  {
    const int o = t >> 2, c0 = (t & 3) << 4;
    const float4* p4 = (const float4*)(wo + o * 64 + c0);
    float4 f0 = p4[0], f1 = p4[1], f2 = p4[2], f3 = p4[3];
    uint4 qa, qb;
    qa.x = (u32)f2bf(f0.x) | ((u32)f2bf(f0.y) << 16);
    qa.y = (u32)f2bf(f0.z) | ((u32)f2bf(f0.w) << 16);
    qa.z = (u32)f2bf(f1.x) | ((u32)f2bf(f1.y) << 16);
    qa.w = (u32)f2bf(f1.z) | ((u32)f2bf(f1.w) << 16);
    qb.x = (u32)f2bf(f2.x) | ((u32)f2bf(f2.y) << 16);
    qb.y = (u32)f2bf(f2.z) | ((u32)f2bf(f2.w) << 16);
    qb.z = (u32)f2bf(f3.x) | ((u32)f2bf(f3.y) << 16);
    qb.w = (u32)f2bf(f3.z) | ((u32)f2bf(f3.w) << 16);
    *(uint4*)&Wl[o * 72 + c0] = qa;
    *(uint4*)&Wl[o * 72 + c0 + 8] = qb;
  }

  // ---- Q fragments (B-operand, scale*log2e pre-folded): 2 q-tiles ----
  bf16x8 qf[2][2];
#pragma unroll
  for (int qt = 0; qt < 2; ++qt) {
    const u16* p = Qg + ((size_t)(b * 4096 + q0 + qt * 16 + l15)) * 64 + qd * 8;
    qf[qt][0] = *(const bf16x8*)p;
    qf[qt][1] = *(const bf16x8*)(p + 32);
  }

  f32x4 zacc[4][2];                            // [ct][qt]
#pragma unroll
  for (int i = 0; i < 4; ++i)
#pragma unroll
    for (int j = 0; j < 2; ++j) {
      f32x4 z = {0.f, 0.f, 0.f, 0.f};
      zacc[i][j] = z;
    }
  float lacc[2] = {0.f, 0.f};

  for (int tile = 0; tile < 16; ++tile) {
    const int nn = w * 1024 + tile * 64;

    // K tile loads first (QK stalls only on these; V issued after last kf use)
    bf16x8 kf[4][2];
#pragma unroll
    for (int mt = 0; mt < 4; ++mt) {
      const u16* p = Kg + ((size_t)(b * 4096 + nn + mt * 16 + l15)) * 64 + qd * 8;
      kf[mt][0] = *(const bf16x8*)p;
      kf[mt][1] = *(const bf16x8*)(p + 32);
    }

    // ---- S^T = K·Q^T, exp2, pack P[q][key] (perm-truncated bf16) ----
#pragma unroll
    for (int qt = 0; qt < 2; ++qt) {
#pragma unroll
      for (int mt = 0; mt < 4; ++mt) {
        f32x4 a = {0.f, 0.f, 0.f, 0.f};
        a = __builtin_amdgcn_mfma_f32_16x16x32_bf16(kf[mt][0], qf[qt][0], a, 0, 0, 0);
        a = __builtin_amdgcn_mfma_f32_16x16x32_bf16(kf[mt][1], qf[qt][1], a, 0, 0, 0);
        float p0 = __builtin_amdgcn_exp2f(a[0]);
        float p1 = __builtin_amdgcn_exp2f(a[1]);
        float p2 = __builtin_amdgcn_exp2f(a[2]);
        float p3 = __builtin_amdgcn_exp2f(a[3]);
        lacc[qt] += (p0 + p1) + (p2 + p3);
        uint2 pw;
        pw.x = packhi(p0, p1);
        pw.y = packhi(p2, p3);
        *(uint2*)&P[(qt * 16 + l15) * 72 + mt * 16 + qd * 4] = pw;
      }
    }

    // V tile loads (latency hidden under exp/pack + other waves on the SIMD)
    bf16x8 vf[4][2];
#pragma unroll
    for (int ct = 0; ct < 4; ++ct) {
      const u16* p = Vg + ((size_t)(b * 64 + ct * 16 + l15)) * 4096 + nn + qd * 8;
      vf[ct][0] = *(const bf16x8*)p;
      vf[ct][1] = *(const bf16x8*)(p + 32);
    }

    // ---- Z^T += V^T · P^T ----
#pragma unroll
    for (int qt = 0; qt < 2; ++qt) {
      bf16x8 pf0 = *(const bf16x8*)&P[(qt * 16 + l15) * 72 + qd * 8];
      bf16x8 pf1 = *(const bf16x8*)&P[(qt * 16 + l15) * 72 + 32 + qd * 8];
#pragma unroll
      for (int ct = 0; ct < 4; ++ct) {
        zacc[ct][qt] = __builtin_amdgcn_mfma_f32_16x16x32_bf16(vf[ct][0], pf0, zacc[ct][qt], 0, 0, 0);
        zacc[ct][qt] = __builtin_amdgcn_mfma_f32_16x16x32_bf16(vf[ct][1], pf1, zacc[ct][qt], 0, 0, 0);
      }
    }
  }

  // ---- epilogue: denominators + unnormalized partial Z ([q][c] bf16) ----
#pragma unroll
  for (int qt = 0; qt < 2; ++qt) {
    float l = lacc[qt];
    l += __shfl_xor(l, 16);
    l += __shfl_xor(l, 32);
    lb[w * 32 + qt * 16 + l15] = l;   // all quads write same value: benign
  }
#pragma unroll
  for (int qt = 0; qt < 2; ++qt)
#pragma unroll
    for (int ct = 0; ct < 4; ++ct) {
      uint2 pw;
      pw.x = packhi(zacc[ct][qt][0], zacc[ct][qt][1]);
      pw.y = packhi(zacc[ct][qt][2], zacc[ct][qt][3]);
      *(uint2*)&P[(qt * 16 + l15) * 72 + ct * 16 + qd * 4] = pw;
    }
  __syncthreads();

  // ---- combine 4 key-splits + normalize -> Zc[q][72] bf16 ----
  {
    const u32* Pu = (const u32*)Pb;            // wave stride 1152 u32, row 36
    u32* Zu = (u32*)Zc;
#pragma unroll
    for (int i = 0; i < 4; ++i) {
      int cell = i * 256 + t;                  // 0..1023
      int q = cell >> 5, cu = cell & 31;       // q 0..31, u32 col 0..31
      float s0 = 0.f, s1 = 0.f;
      float den = 0.f;
#pragma unroll
      for (int ww = 0; ww < 4; ++ww) {
        u32 v = Pu[ww * 1152 + q * 36 + cu];
        s0 += bflo(v);
        s1 += bfhi(v);
        den += lb[ww * 32 + q];
      }
      float inv = 1.f / den;
      Zu[q * 36 + cu] = packhi(s0 * inv, s1 * inv);
    }
  }
  __syncthreads();

  // ---- Y = affine(Wo · Z): wave w -> q rows (w&1)*16..+15, o-half w>>1 ----
  {
    const int qr = w & 1, oh = w >> 1;
    bf16x8 af0 = *(const bf16x8*)&Zc[(qr * 16 + l15) * 72 + qd * 8];
    bf16x8 af1 = *(const bf16x8*)&Zc[(qr * 16 + l15) * 72 + 32 + qd * 8];
#pragma unroll
    for (int ni = 0; ni < 2; ++ni) {
      const int nt = oh * 2 + ni;
      bf16x8 b0 = *(const bf16x8*)&Wl[(nt * 16 + l15) * 72 + qd * 8];
      bf16x8 b1 = *(const bf16x8*)&Wl[(nt * 16 + l15) * 72 + 32 + qd * 8];
      f32x4 y = {0.f, 0.f, 0.f, 0.f};
      y = __builtin_amdgcn_mfma_f32_16x16x32_bf16(af0, b0, y, 0, 0, 0);
      y = __builtin_amdgcn_mfma_f32_16x16x32_bf16(af1, b1, y, 0, 0, 0);
      const int o = nt * 16 + l15;
      float A = gam[o] * __frsqrt_rn(var[o] + 1e-5f);
      float B = (bo[o] - mean[o]) * A + bet[o];
#pragma unroll
      for (int e = 0; e < 4; ++e) {
        float v = y[e] * A + B;
        size_t tok = (size_t)(b * 4096 + q0 + qr * 16 + qd * 4 + e);
        Ya[tok * 64 + o] = (u16)(__float_as_uint(v) >> 16);
      }
    }
  }
}

// ---------------------------------------------------------------------------
// Kernel 3: bilinear 2x upsample of Ya + LeakyReLU + residual.
// grid 1024 x 256: thread = one (b,i,j,channel-half) — 2 threads/pixel,
// 32 channels each. Was 1 wave/SIMD (512 blocks, 2 blocks/CU); channel-split
// doubles the grid -> 4 blocks/CU = 4 waves/SIMD for latency hiding.
// Ya is channel-innermost -> each corner read is a contiguous 64 B run.
// ---------------------------------------------------------------------------
__global__ __launch_bounds__(256, 4) void k_out(
    const u16* __restrict__ Ya, const float* __restrict__ rgb,
    float* __restrict__ out)
{
  const int tid = blockIdx.x * 256 + threadIdx.x;  // 0..262143
  const int cg  = tid & 1;                         // channel half (o = cg*32..)
  const int px  = tid >> 1;                        // 0..131071
  const int j = px & 127;
  const int i = (px >> 7) & 127;
  const int b = px >> 14;

  float ys = fmaxf((i + 0.5f) * 0.5f - 0.5f, 0.f);
  int   y0 = (int)ys;
  float wy = ys - (float)y0;
  int   y1 = min(y0 + 1, 63);
  float xs = fmaxf((j + 0.5f) * 0.5f - 0.5f, 0.f);
  int   x0 = (int)xs;
  float wx = xs - (float)x0;
  int   x1 = min(x0 + 1, 63);
  float w00 = (1.f - wy) * (1.f - wx), w01 = (1.f - wy) * wx;
  float w10 = wy * (1.f - wx),         w11 = wy * wx;

  const u16* yb = Ya + (size_t)b * 262144;
  const int b00 = (y0 * 64 + x0) * 64, b01 = (y0 * 64 + x1) * 64;
  const int b10 = (y1 * 64 + x0) * 64, b11 = (y1 * 64 + x1) * 64;
  const int ch0 = cg * 4;                          // uint4-granule base

#pragma unroll
  for (int ch = 0; ch < 4; ++ch) {
    const int cc = ch0 + ch;
    uint4 a00 = *(const uint4*)&yb[b00 + cc * 8];
    uint4 a01 = *(const uint4*)&yb[b01 + cc * 8];
    uint4 a10 = *(const uint4*)&yb[b10 + cc * 8];
    uint4 a11 = *(const uint4*)&yb[b11 + cc * 8];
    const u32* u00 = (const u32*)&a00;
    const u32* u01 = (const u32*)&a01;
    const u32* u10 = (const u32*)&a10;
    const u32* u11 = (const u32*)&a11;
#pragma unroll
    for (int e = 0; e < 8; ++e) {
      const int wd = e >> 1;
      float c00 = (e & 1) ? bfhi(u00[wd]) : bflo(u00[wd]);
      float c01 = (e & 1) ? bfhi(u01[wd]) : bflo(u01[wd]);
      float c10 = (e & 1) ? bfhi(u10[wd]) : bflo(u10[wd]);
      float c11 = (e & 1) ? bfhi(u11[wd]) : bflo(u11[wd]);
      float v = w00 * c00 + w01 * c01 + w10 * c10 + w11 * c11;
      v = (v >= 0.f) ? v : 0.2f * v;
      const int o = cc * 8 + e;
      const size_t oi = ((size_t)((b * 64 + o) * 128 + i)) * 128 + j;
      out[oi] = rgb[oi] + v;
    }
  }
}

// ---------------------------------------------------------------------------
extern "C" void kernel_launch(void* const* d_in, const int* in_sizes, int n_in,
                              void* d_out, int out_size, void* d_ws, size_t ws_size,
                              hipStream_t stream) {
  (void)in_sizes; (void)n_in; (void)out_size; (void)ws_size;
  const float* rgb  = (const float*)d_in[0];
  const float* freq = (const float*)d_in[1];
  const float* wq   = (const float*)d_in[2];
  const float* bq   = (const float*)d_in[3];
  const float* wk   = (const float*)d_in[4];
  const float* bk   = (const float*)d_in[5];
  const float* wv   = (const float*)d_in[6];
  const float* bv   = (const float*)d_in[7];
  const float* wo   = (const float*)d_in[8];
  const float* bo   = (const float*)d_in[9];
  const float* gam  = (const float*)d_in[10];
  const float* bet  = (const float*)d_in[11];
  const float* mean = (const float*)d_in[12];
  const float* var  = (const float*)d_in[13];

  char* ws = (char*)d_ws;
  u16* Qw = (u16*)(ws);               // 8*4096*64 bf16 = 4 MiB
  u16* Kw = (u16*)(ws + 4194304);     // 4 MiB
  u16* Vw = (u16*)(ws + 8388608);     // 4 MiB (transposed [b][c][n])
  u16* Yw = (u16*)(ws + 12582912);    // 4 MiB  Ya[b][n][64] bf16

  k_qkv<<<dim3(1024), dim3(256), 0, stream>>>(rgb, freq, wq, bq, wk, bk, wv, bv,
                                              Qw, Kw, Vw);
  k_attn<<<dim3(8, 128), dim3(256), 0, stream>>>(Qw, Kw, Vw, wo, bo, gam, bet,
                                                 mean, var, Yw);
  k_out<<<dim3(1024), dim3(256), 0, stream>>>(Yw, rgb, (float*)d_out);
}

// Round 5
// 257.751 us; speedup vs baseline: 1.1156x; 1.0268x over previous
//
#include <hip/hip_runtime.h>
#include <hip/hip_bf16.h>

typedef unsigned short u16;
typedef unsigned int   u32;
typedef __attribute__((ext_vector_type(8))) short bf16x8;
typedef __attribute__((ext_vector_type(4))) float f32x4;

__device__ __forceinline__ u16 f2bf(float f) {
  u32 u = __float_as_uint(f);
  u32 r = u + 0x7fffu + ((u >> 16) & 1u);
  return (u16)(r >> 16);
}
__device__ __forceinline__ float bflo(u32 u) { return __uint_as_float(u << 16); }
__device__ __forceinline__ float bfhi(u32 u) { return __uint_as_float(u & 0xffff0000u); }
// pack (hi16(b)<<16)|hi16(a) in one v_perm (truncation-to-bf16; bias cancels
// in softmax normalization, ~0.4% rel elsewhere — noise vs 0.109 threshold)
__device__ __forceinline__ u32 packhi(float a, float b) {
  return __builtin_amdgcn_perm(__float_as_uint(b), __float_as_uint(a), 0x07060302u);
}

// ---------------------------------------------------------------------------
// Kernel 1: avgpool 2x2 + Q/K/V 1x1-conv projections via MFMA.
// grid 1024 x 256 (4 waves). side = blockIdx&1 (0: rgb->Q, 1: freq->K,V).
// Q,K stored [b][n][64] bf16; V stored [b][64][n] bf16.
// Q pre-scaled by hid^-0.5 * log2(e) = 0.125*1.4426950 so k_attn can use
// exp2 directly (saves one v_mul per softmax element).
// ---------------------------------------------------------------------------
__global__ __launch_bounds__(256, 4) void k_qkv(
    const float* __restrict__ rgb, const float* __restrict__ freq,
    const float* __restrict__ wq, const float* __restrict__ bq,
    const float* __restrict__ wk, const float* __restrict__ bk,
    const float* __restrict__ wv, const float* __restrict__ bv,
    u16* __restrict__ Qo, u16* __restrict__ Ko, u16* __restrict__ Vo)
{
  __shared__ __align__(16) u16 sm[3 * 4608];
  u16* X  = sm;             // [64][72] pooled input tokens
  u16* W0 = sm + 4608;      // [64][72] wq or wk
  u16* W1 = sm + 9216;      // [64][72] wv (side 1 only)

  const int t    = threadIdx.x;
  const int side = blockIdx.x & 1;
  const int seg  = blockIdx.x >> 1;       // 0..511
  const int idx0 = seg * 64;              // global token base (b*4096+n)
  const int bb   = idx0 >> 12;
  const int n0   = idx0 & 4095;
  const int h    = n0 >> 6;               // pooled row (uniform per block)
  const float* src = side ? freq : rgb;

  // ---- stage pooled X: 64 tokens (one pooled row) x 64 ch ----
  const size_t sbase = (size_t)bb * 64 * 16384 + (size_t)(2 * h) * 128;
  for (int i = 0; i < 2; ++i) {
    int cell = i * 256 + t;               // 0..511
    int tok  = cell & 63;                 // lane-consecutive -> coalesced
    int grp  = cell >> 6;                 // channel granule 0..7
    const float* p0 = src + sbase + 2 * tok + (size_t)(grp * 8) * 16384;
    u32 pk[4];
#pragma unroll
    for (int cc = 0; cc < 8; cc += 2) {
      const float* pa = p0 + (size_t)cc * 16384;
      float2 a0 = *(const float2*)pa;
      float2 a1 = *(const float2*)(pa + 128);
      float v0 = 0.25f * ((a0.x + a0.y) + (a1.x + a1.y));
      const float* pb = pa + 16384;
      float2 b0 = *(const float2*)pb;
      float2 b1 = *(const float2*)(pb + 128);
      float v1 = 0.25f * ((b0.x + b0.y) + (b1.x + b1.y));
      pk[cc >> 1] = (u32)f2bf(v0) | ((u32)f2bf(v1) << 16);
    }
    uint4 q4; q4.x = pk[0]; q4.y = pk[1]; q4.z = pk[2]; q4.w = pk[3];
    *(uint4*)&X[tok * 72 + grp * 8] = q4;
  }
  // ---- stage weights, float4-coalesced: thread -> (o = t>>2, c0 = (t&3)*16)
  {
    const int o = t >> 2, c0 = (t & 3) << 4;
    const float4* p4 = (const float4*)((side ? wk : wq) + o * 64 + c0);
    float4 f0 = p4[0], f1 = p4[1], f2 = p4[2], f3 = p4[3];
    uint4 qa, qb;
    qa.x = (u32)f2bf(f0.x) | ((u32)f2bf(f0.y) << 16);
    qa.y = (u32)f2bf(f0.z) | ((u32)f2bf(f0.w) << 16);
    qa.z = (u32)f2bf(f1.x) | ((u32)f2bf(f1.y) << 16);
    qa.w = (u32)f2bf(f1.z) | ((u32)f2bf(f1.w) << 16);
    qb.x = (u32)f2bf(f2.x) | ((u32)f2bf(f2.y) << 16);
    qb.y = (u32)f2bf(f2.z) | ((u32)f2bf(f2.w) << 16);
    qb.z = (u32)f2bf(f3.x) | ((u32)f2bf(f3.y) << 16);
    qb.w = (u32)f2bf(f3.z) | ((u32)f2bf(f3.w) << 16);
    *(uint4*)&W0[o * 72 + c0] = qa;
    *(uint4*)&W0[o * 72 + c0 + 8] = qb;
    if (side) {
      const float4* v4 = (const float4*)(wv + o * 64 + c0);
      float4 g0 = v4[0], g1 = v4[1], g2 = v4[2], g3 = v4[3];
      qa.x = (u32)f2bf(g0.x) | ((u32)f2bf(g0.y) << 16);
      qa.y = (u32)f2bf(g0.z) | ((u32)f2bf(g0.w) << 16);
      qa.z = (u32)f2bf(g1.x) | ((u32)f2bf(g1.y) << 16);
      qa.w = (u32)f2bf(g1.z) | ((u32)f2bf(g1.w) << 16);
      qb.x = (u32)f2bf(g2.x) | ((u32)f2bf(g2.y) << 16);
      qb.y = (u32)f2bf(g2.z) | ((u32)f2bf(g2.w) << 16);
      qb.z = (u32)f2bf(g3.x) | ((u32)f2bf(g3.y) << 16);
      qb.w = (u32)f2bf(g3.z) | ((u32)f2bf(g3.w) << 16);
      *(uint4*)&W1[o * 72 + c0] = qa;
      *(uint4*)&W1[o * 72 + c0 + 8] = qb;
    }
  }
  __syncthreads();

  const int lane = t & 63, w = t >> 6;
  const int l15 = lane & 15, qd = lane >> 4;
  const int tb = w * 16;                  // wave's 16 tokens

  bf16x8 af0 = *(const bf16x8*)&X[(tb + l15) * 72 + qd * 8];
  bf16x8 af1 = *(const bf16x8*)&X[(tb + l15) * 72 + 32 + qd * 8];

  // ---- Q (side 0) / K (side 1): A = X (rows tok), B = W0 (cols o) ----
  f32x4 acc[4];
#pragma unroll
  for (int nt = 0; nt < 4; ++nt) {
    bf16x8 b0 = *(const bf16x8*)&W0[(nt * 16 + l15) * 72 + qd * 8];
    bf16x8 b1 = *(const bf16x8*)&W0[(nt * 16 + l15) * 72 + 32 + qd * 8];
    f32x4 a = {0.f, 0.f, 0.f, 0.f};
    a = __builtin_amdgcn_mfma_f32_16x16x32_bf16(af0, b0, a, 0, 0, 0);
    a = __builtin_amdgcn_mfma_f32_16x16x32_bf16(af1, b1, a, 0, 0, 0);
    acc[nt] = a;
  }
  {
    const float* bias0 = side ? bk : bq;
    // Q scale = hid^-0.5 * log2(e); K unscaled
    const float sc = side ? 1.f : 0.18033688f;
    u16* dst0 = side ? Ko : Qo;
#pragma unroll
    for (int nt = 0; nt < 4; ++nt) {
      float bia = bias0[nt * 16 + l15];
#pragma unroll
      for (int e = 0; e < 4; ++e) {
        int tok = idx0 + tb + qd * 4 + e;     // D row = token
        dst0[(size_t)tok * 64 + nt * 16 + l15] = f2bf((acc[nt][e] + bia) * sc);
      }
    }
  }

  if (side) {
    // ---- V: A = Wv (rows c), B = X (cols tok) -> D = V^T directly ----
    f32x4 accv[4];
#pragma unroll
    for (int ct = 0; ct < 4; ++ct) {
      bf16x8 a0 = *(const bf16x8*)&W1[(ct * 16 + l15) * 72 + qd * 8];
      bf16x8 a1 = *(const bf16x8*)&W1[(ct * 16 + l15) * 72 + 32 + qd * 8];
      f32x4 a = {0.f, 0.f, 0.f, 0.f};
      a = __builtin_amdgcn_mfma_f32_16x16x32_bf16(a0, af0, a, 0, 0, 0);
      a = __builtin_amdgcn_mfma_f32_16x16x32_bf16(a1, af1, a, 0, 0, 0);
      accv[ct] = a;
    }
#pragma unroll
    for (int ct = 0; ct < 4; ++ct) {
#pragma unroll
      for (int e = 0; e < 4; ++e) {
        int c = ct * 16 + qd * 4 + e;          // D row = V channel
        float v = accv[ct][e] + bv[c];
        Vo[((size_t)(bb * 64 + c)) * 4096 + n0 + tb + l15] = f2bf(v);
      }
    }
  }
}

// ---------------------------------------------------------------------------
// Kernel 2: attention + fused output-conv/BN epilogue, barrier-free K-loop.
// grid (8 b, 128 qtile) x 256 threads = 4 independent waves.
// Register-budget model (r0-r4 evidence + m69 occupancy quanta): the
// launch_bounds 2nd arg sets the TOTAL unified-file budget 512/arg per wave;
// occupancy quantizes at {64,128,256} regs -> {8,4,2} waves/SIMD.
//   r0: (256,2) cap 256, live ~150 -> no spill, but 2 waves/SIMD (74us)
//   r3/r4: cap 128, live ~150 -> SPILL (133us) despite 4 waves/SIMD
// Fix: shrink the live set below 128 so (256,4) = 4 waves/SIMD AND no spill.
//   - QK phase: mt-outer, ONE K-subtile in regs at a time (8 regs, was 32);
//     the 4 serialized per-tile K loads are hidden by TLP (4 waves/SIMD).
//   - PV phase: V in 2-subtile chunks (16 regs, was 32); P fragments
//     re-read from LDS per chunk (+8 ds_read_b128/tile, cheap).
// Live set ~= qf16 + kf8 + vf16 + pf8 + zacc32 + addr ~20 ~= 100 < 128.
// Wave w = key-split w (keys w*1024..+1024, 16 tiles of 64), all 32 block-q.
// No-max softmax (exp2; log2e folded into Q scale); partials combine
// additively. Epilogue: combine 4 partials + normalize Z in LDS (bf16), then
// Y = BNaffine(Wo·Z) via MFMA, store Ya[b][n][64] bf16. Conv/BN commute with
// the bilinear resize — LeakyReLU applied post-interp in k_out.
// ---------------------------------------------------------------------------
__global__ __launch_bounds__(256, 4) void k_attn(
    const u16* __restrict__ Qg, const u16* __restrict__ Kg,
    const u16* __restrict__ Vg,
    const float* __restrict__ wo, const float* __restrict__ bo,
    const float* __restrict__ gam, const float* __restrict__ bet,
    const float* __restrict__ mean, const float* __restrict__ var,
    u16* __restrict__ Ya)
{
  __shared__ __align__(16) u16 Pb[4 * 2304];   // per-wave [32 q][72] P / partial-Z
  __shared__ __align__(16) u16 Wl[4608];       // Wo [64 o][72]
  __shared__ __align__(16) u16 Zc[2304];       // combined Z [32 q][72]
  __shared__ float lb[128];                    // [wave][32 q] denominators

  const int b  = blockIdx.x;                   // batch -> XCD affinity
  const int q0 = blockIdx.y * 32;
  const int t  = threadIdx.x;
  const int lane = t & 63, w = t >> 6;         // w = key-split 0..3
  const int l15 = lane & 15, qd = lane >> 4;
  u16* P = Pb + w * 2304;

  // ---- stage Wo (bf16, rounded) for the epilogue GEMM ----
  {
    const int o = t >> 2, c0 = (t & 3) << 4;
    const float4* p4 = (const float4*)(wo + o * 64 + c0);
    float4 f0 = p4[0], f1 = p4[1], f2 = p4[2], f3 = p4[3];
    uint4 qa, qb;
    qa.x = (u32)f2bf(f0.x) | ((u32)f2bf(f0.y) << 16);
    qa.y = (u32)f2bf(f0.z) | ((u32)f2bf(f0.w) << 16);
    qa.z = (u32)f2bf(f1.x) | ((u32)f2bf(f1.y) << 16);
    qa.w = (u32)f2bf(f1.z) | ((u32)f2bf(f1.w) << 16);
    qb.x = (u32)f2bf(f2.x) | ((u32)f2bf(f2.y) << 16);
    qb.y = (u32)f2bf(f2.z) | ((u32)f2bf(f2.w) << 16);
    qb.z = (u32)f2bf(f3.x) | ((u32)f2bf(f3.y) << 16);
    qb.w = (u32)f2bf(f3.z) | ((u32)f2bf(f3.w) << 16);
    *(uint4*)&Wl[o * 72 + c0] = qa;
    *(uint4*)&Wl[o * 72 + c0 + 8] = qb;
  }

  // ---- Q fragments (B-operand, scale*log2e pre-folded): 2 q-tiles ----
  bf16x8 qf[2][2];
#pragma unroll
  for (int qt = 0; qt < 2; ++qt) {
    const u16* p = Qg + ((size_t)(b * 4096 + q0 + qt * 16 + l15)) * 64 + qd * 8;
    qf[qt][0] = *(const bf16x8*)p;
    qf[qt][1] = *(const bf16x8*)(p + 32);
  }

  f32x4 zacc[4][2];                            // [ct][qt]
#pragma unroll
  for (int i = 0; i < 4; ++i)
#pragma unroll
    for (int j = 0; j < 2; ++j) {
      f32x4 z = {0.f, 0.f, 0.f, 0.f};
      zacc[i][j] = z;
    }
  float lacc[2] = {0.f, 0.f};

  for (int tile = 0; tile < 16; ++tile) {
    const int nn = w * 1024 + tile * 64;

    // ---- QK phase: mt-outer, one K-subtile live at a time (8 VGPRs) ----
#pragma unroll
    for (int mt = 0; mt < 4; ++mt) {
      const u16* pk = Kg + ((size_t)(b * 4096 + nn + mt * 16 + l15)) * 64 + qd * 8;
      bf16x8 k0 = *(const bf16x8*)pk;
      bf16x8 k1 = *(const bf16x8*)(pk + 32);
#pragma unroll
      for (int qt = 0; qt < 2; ++qt) {
        f32x4 a = {0.f, 0.f, 0.f, 0.f};
        a = __builtin_amdgcn_mfma_f32_16x16x32_bf16(k0, qf[qt][0], a, 0, 0, 0);
        a = __builtin_amdgcn_mfma_f32_16x16x32_bf16(k1, qf[qt][1], a, 0, 0, 0);
        float p0 = __builtin_amdgcn_exp2f(a[0]);
        float p1 = __builtin_amdgcn_exp2f(a[1]);
        float p2 = __builtin_amdgcn_exp2f(a[2]);
        float p3 = __builtin_amdgcn_exp2f(a[3]);
        lacc[qt] += (p0 + p1) + (p2 + p3);
        uint2 pw;
        pw.x = packhi(p0, p1);
        pw.y = packhi(p2, p3);
        *(uint2*)&P[(qt * 16 + l15) * 72 + mt * 16 + qd * 4] = pw;
      }
    }

    // ---- PV phase: V in 2-subtile chunks (16 VGPRs); P re-read per chunk --
#pragma unroll
    for (int cp = 0; cp < 2; ++cp) {
      const u16* pv0 = Vg + ((size_t)(b * 64 + (cp * 2) * 16 + l15)) * 4096 + nn + qd * 8;
      const u16* pv1 = Vg + ((size_t)(b * 64 + (cp * 2 + 1) * 16 + l15)) * 4096 + nn + qd * 8;
      bf16x8 v00 = *(const bf16x8*)pv0;
      bf16x8 v01 = *(const bf16x8*)(pv0 + 32);
      bf16x8 v10 = *(const bf16x8*)pv1;
      bf16x8 v11 = *(const bf16x8*)(pv1 + 32);
#pragma unroll
      for (int qt = 0; qt < 2; ++qt) {
        bf16x8 pf0 = *(const bf16x8*)&P[(qt * 16 + l15) * 72 + qd * 8];
        bf16x8 pf1 = *(const bf16x8*)&P[(qt * 16 + l15) * 72 + 32 + qd * 8];
        zacc[cp * 2][qt]     = __builtin_amdgcn_mfma_f32_16x16x32_bf16(v00, pf0, zacc[cp * 2][qt], 0, 0, 0);
        zacc[cp * 2][qt]     = __builtin_amdgcn_mfma_f32_16x16x32_bf16(v01, pf1, zacc[cp * 2][qt], 0, 0, 0);
        zacc[cp * 2 + 1][qt] = __builtin_amdgcn_mfma_f32_16x16x32_bf16(v10, pf0, zacc[cp * 2 + 1][qt], 0, 0, 0);
        zacc[cp * 2 + 1][qt] = __builtin_amdgcn_mfma_f32_16x16x32_bf16(v11, pf1, zacc[cp * 2 + 1][qt], 0, 0, 0);
      }
    }
  }

  // ---- epilogue: denominators + unnormalized partial Z ([q][c] bf16) ----
#pragma unroll
  for (int qt = 0; qt < 2; ++qt) {
    float l = lacc[qt];
    l += __shfl_xor(l, 16);
    l += __shfl_xor(l, 32);
    lb[w * 32 + qt * 16 + l15] = l;   // all quads write same value: benign
  }
#pragma unroll
  for (int qt = 0; qt < 2; ++qt)
#pragma unroll
    for (int ct = 0; ct < 4; ++ct) {
      uint2 pw;
      pw.x = packhi(zacc[ct][qt][0], zacc[ct][qt][1]);
      pw.y = packhi(zacc[ct][qt][2], zacc[ct][qt][3]);
      *(uint2*)&P[(qt * 16 + l15) * 72 + ct * 16 + qd * 4] = pw;
    }
  __syncthreads();

  // ---- combine 4 key-splits + normalize -> Zc[q][72] bf16 ----
  {
    const u32* Pu = (const u32*)Pb;            // wave stride 1152 u32, row 36
    u32* Zu = (u32*)Zc;
#pragma unroll
    for (int i = 0; i < 4; ++i) {
      int cell = i * 256 + t;                  // 0..1023
      int q = cell >> 5, cu = cell & 31;       // q 0..31, u32 col 0..31
      float s0 = 0.f, s1 = 0.f;
      float den = 0.f;
#pragma unroll
      for (int ww = 0; ww < 4; ++ww) {
        u32 v = Pu[ww * 1152 + q * 36 + cu];
        s0 += bflo(v);
        s1 += bfhi(v);
        den += lb[ww * 32 + q];
      }
      float inv = 1.f / den;
      Zu[q * 36 + cu] = packhi(s0 * inv, s1 * inv);
    }
  }
  __syncthreads();

  // ---- Y = affine(Wo · Z): wave w -> q rows (w&1)*16..+15, o-half w>>1 ----
  {
    const int qr = w & 1, oh = w >> 1;
    bf16x8 af0 = *(const bf16x8*)&Zc[(qr * 16 + l15) * 72 + qd * 8];
    bf16x8 af1 = *(const bf16x8*)&Zc[(qr * 16 + l15) * 72 + 32 + qd * 8];
#pragma unroll
    for (int ni = 0; ni < 2; ++ni) {
      const int nt = oh * 2 + ni;
      bf16x8 b0 = *(const bf16x8*)&Wl[(nt * 16 + l15) * 72 + qd * 8];
      bf16x8 b1 = *(const bf16x8*)&Wl[(nt * 16 + l15) * 72 + 32 + qd * 8];
      f32x4 y = {0.f, 0.f, 0.f, 0.f};
      y = __builtin_amdgcn_mfma_f32_16x16x32_bf16(af0, b0, y, 0, 0, 0);
      y = __builtin_amdgcn_mfma_f32_16x16x32_bf16(af1, b1, y, 0, 0, 0);
      const int o = nt * 16 + l15;
      float A = gam[o] * __frsqrt_rn(var[o] + 1e-5f);
      float B = (bo[o] - mean[o]) * A + bet[o];
#pragma unroll
      for (int e = 0; e < 4; ++e) {
        float v = y[e] * A + B;
        size_t tok = (size_t)(b * 4096 + q0 + qr * 16 + qd * 4 + e);
        Ya[tok * 64 + o] = (u16)(__float_as_uint(v) >> 16);
      }
    }
  }
}

// ---------------------------------------------------------------------------
// Kernel 3: bilinear 2x upsample of Ya + LeakyReLU + residual.
// grid 1024 x 256: thread = one (b,i,j,channel-half) — 2 threads/pixel,
// 32 channels each -> 4 blocks/CU = 4 waves/SIMD for latency hiding.
// Ya is channel-innermost -> each corner read is a contiguous 64 B run.
// ---------------------------------------------------------------------------
__global__ __launch_bounds__(256, 4) void k_out(
    const u16* __restrict__ Ya, const float* __restrict__ rgb,
    float* __restrict__ out)
{
  const int tid = blockIdx.x * 256 + threadIdx.x;  // 0..262143
  const int cg  = tid & 1;                         // channel half (o = cg*32..)
  const int px  = tid >> 1;                        // 0..131071
  const int j = px & 127;
  const int i = (px >> 7) & 127;
  const int b = px >> 14;

  float ys = fmaxf((i + 0.5f) * 0.5f - 0.5f, 0.f);
  int   y0 = (int)ys;
  float wy = ys - (float)y0;
  int   y1 = min(y0 + 1, 63);
  float xs = fmaxf((j + 0.5f) * 0.5f - 0.5f, 0.f);
  int   x0 = (int)xs;
  float wx = xs - (float)x0;
  int   x1 = min(x0 + 1, 63);
  float w00 = (1.f - wy) * (1.f - wx), w01 = (1.f - wy) * wx;
  float w10 = wy * (1.f - wx),         w11 = wy * wx;

  const u16* yb = Ya + (size_t)b * 262144;
  const int b00 = (y0 * 64 + x0) * 64, b01 = (y0 * 64 + x1) * 64;
  const int b10 = (y1 * 64 + x0) * 64, b11 = (y1 * 64 + x1) * 64;
  const int ch0 = cg * 4;                          // uint4-granule base

#pragma unroll
  for (int ch = 0; ch < 4; ++ch) {
    const int cc = ch0 + ch;
    uint4 a00 = *(const uint4*)&yb[b00 + cc * 8];
    uint4 a01 = *(const uint4*)&yb[b01 + cc * 8];
    uint4 a10 = *(const uint4*)&yb[b10 + cc * 8];
    uint4 a11 = *(const uint4*)&yb[b11 + cc * 8];
    const u32* u00 = (const u32*)&a00;
    const u32* u01 = (const u32*)&a01;
    const u32* u10 = (const u32*)&a10;
    const u32* u11 = (const u32*)&a11;
#pragma unroll
    for (int e = 0; e < 8; ++e) {
      const int wd = e >> 1;
      float c00 = (e & 1) ? bfhi(u00[wd]) : bflo(u00[wd]);
      float c01 = (e & 1) ? bfhi(u01[wd]) : bflo(u01[wd]);
      float c10 = (e & 1) ? bfhi(u10[wd]) : bflo(u10[wd]);
      float c11 = (e & 1) ? bfhi(u11[wd]) : bflo(u11[wd]);
      float v = w00 * c00 + w01 * c01 + w10 * c10 + w11 * c11;
      v = (v >= 0.f) ? v : 0.2f * v;
      const int o = cc * 8 + e;
      const size_t oi = ((size_t)((b * 64 + o) * 128 + i)) * 128 + j;
      out[oi] = rgb[oi] + v;
    }
  }
}

// ---------------------------------------------------------------------------
extern "C" void kernel_launch(void* const* d_in, const int* in_sizes, int n_in,
                              void* d_out, int out_size, void* d_ws, size_t ws_size,
                              hipStream_t stream) {
  (void)in_sizes; (void)n_in; (void)out_size; (void)ws_size;
  const float* rgb  = (const float*)d_in[0];
  const float* freq = (const float*)d_in[1];
  const float* wq   = (const float*)d_in[2];
  const float* bq   = (const float*)d_in[3];
  const float* wk   = (const float*)d_in[4];
  const float* bk   = (const float*)d_in[5];
  const float* wv   = (const float*)d_in[6];
  const float* bv   = (const float*)d_in[7];
  const float* wo   = (const float*)d_in[8];
  const float* bo   = (const float*)d_in[9];
  const float* gam  = (const float*)d_in[10];
  const float* bet  = (const float*)d_in[11];
  const float* mean = (const float*)d_in[12];
  const float* var  = (const float*)d_in[13];

  char* ws = (char*)d_ws;
  u16* Qw = (u16*)(ws);               // 8*4096*64 bf16 = 4 MiB
  u16* Kw = (u16*)(ws + 4194304);     // 4 MiB
  u16* Vw = (u16*)(ws + 8388608);     // 4 MiB (transposed [b][c][n])
  u16* Yw = (u16*)(ws + 12582912);    // 4 MiB  Ya[b][n][64] bf16

  k_qkv<<<dim3(1024), dim3(256), 0, stream>>>(rgb, freq, wq, bq, wk, bk, wv, bv,
                                              Qw, Kw, Vw);
  k_attn<<<dim3(8, 128), dim3(256), 0, stream>>>(Qw, Kw, Vw, wo, bo, gam, bet,
                                                 mean, var, Yw);
  k_out<<<dim3(1024), dim3(256), 0, stream>>>(Yw, rgb, (float*)d_out);
}

// Round 6
// 257.377 us; speedup vs baseline: 1.1172x; 1.0015x over previous
//
#include <hip/hip_runtime.h>
#include <hip/hip_bf16.h>

typedef unsigned short u16;
typedef unsigned int   u32;
typedef __attribute__((ext_vector_type(8))) short bf16x8;
typedef __attribute__((ext_vector_type(4))) float f32x4;

__device__ __forceinline__ u16 f2bf(float f) {
  u32 u = __float_as_uint(f);
  u32 r = u + 0x7fffu + ((u >> 16) & 1u);
  return (u16)(r >> 16);
}
__device__ __forceinline__ float bflo(u32 u) { return __uint_as_float(u << 16); }
__device__ __forceinline__ float bfhi(u32 u) { return __uint_as_float(u & 0xffff0000u); }
// pack (hi16(b)<<16)|hi16(a) in one v_perm (truncation-to-bf16; bias cancels
// in softmax normalization, ~0.4% rel elsewhere — noise vs 0.109 threshold)
__device__ __forceinline__ u32 packhi(float a, float b) {
  return __builtin_amdgcn_perm(__float_as_uint(b), __float_as_uint(a), 0x07060302u);
}

// ---------------------------------------------------------------------------
// Kernel 1: avgpool 2x2 + Q/K/V 1x1-conv projections via MFMA.
// grid 1024 x 256 (4 waves). side = blockIdx&1 (0: rgb->Q, 1: freq->K,V).
// Q,K stored [b][n][64] bf16; V stored [b][64][n] bf16.
// Q pre-scaled by hid^-0.5 * log2(e) = 0.125*1.4426950 so k_attn can use
// exp2 directly (saves one v_mul per softmax element).
// ---------------------------------------------------------------------------
__global__ __launch_bounds__(256, 4) void k_qkv(
    const float* __restrict__ rgb, const float* __restrict__ freq,
    const float* __restrict__ wq, const float* __restrict__ bq,
    const float* __restrict__ wk, const float* __restrict__ bk,
    const float* __restrict__ wv, const float* __restrict__ bv,
    u16* __restrict__ Qo, u16* __restrict__ Ko, u16* __restrict__ Vo)
{
  __shared__ __align__(16) u16 sm[3 * 4608];
  u16* X  = sm;             // [64][72] pooled input tokens
  u16* W0 = sm + 4608;      // [64][72] wq or wk
  u16* W1 = sm + 9216;      // [64][72] wv (side 1 only)

  const int t    = threadIdx.x;
  const int side = blockIdx.x & 1;
  const int seg  = blockIdx.x >> 1;       // 0..511
  const int idx0 = seg * 64;              // global token base (b*4096+n)
  const int bb   = idx0 >> 12;
  const int n0   = idx0 & 4095;
  const int h    = n0 >> 6;               // pooled row (uniform per block)
  const float* src = side ? freq : rgb;

  // ---- stage pooled X: 64 tokens (one pooled row) x 64 ch ----
  const size_t sbase = (size_t)bb * 64 * 16384 + (size_t)(2 * h) * 128;
  for (int i = 0; i < 2; ++i) {
    int cell = i * 256 + t;               // 0..511
    int tok  = cell & 63;                 // lane-consecutive -> coalesced
    int grp  = cell >> 6;                 // channel granule 0..7
    const float* p0 = src + sbase + 2 * tok + (size_t)(grp * 8) * 16384;
    u32 pk[4];
#pragma unroll
    for (int cc = 0; cc < 8; cc += 2) {
      const float* pa = p0 + (size_t)cc * 16384;
      float2 a0 = *(const float2*)pa;
      float2 a1 = *(const float2*)(pa + 128);
      float v0 = 0.25f * ((a0.x + a0.y) + (a1.x + a1.y));
      const float* pb = pa + 16384;
      float2 b0 = *(const float2*)pb;
      float2 b1 = *(const float2*)(pb + 128);
      float v1 = 0.25f * ((b0.x + b0.y) + (b1.x + b1.y));
      pk[cc >> 1] = (u32)f2bf(v0) | ((u32)f2bf(v1) << 16);
    }
    uint4 q4; q4.x = pk[0]; q4.y = pk[1]; q4.z = pk[2]; q4.w = pk[3];
    *(uint4*)&X[tok * 72 + grp * 8] = q4;
  }
  // ---- stage weights, float4-coalesced: thread -> (o = t>>2, c0 = (t&3)*16)
  {
    const int o = t >> 2, c0 = (t & 3) << 4;
    const float4* p4 = (const float4*)((side ? wk : wq) + o * 64 + c0);
    float4 f0 = p4[0], f1 = p4[1], f2 = p4[2], f3 = p4[3];
    uint4 qa, qb;
    qa.x = (u32)f2bf(f0.x) | ((u32)f2bf(f0.y) << 16);
    qa.y = (u32)f2bf(f0.z) | ((u32)f2bf(f0.w) << 16);
    qa.z = (u32)f2bf(f1.x) | ((u32)f2bf(f1.y) << 16);
    qa.w = (u32)f2bf(f1.z) | ((u32)f2bf(f1.w) << 16);
    qb.x = (u32)f2bf(f2.x) | ((u32)f2bf(f2.y) << 16);
    qb.y = (u32)f2bf(f2.z) | ((u32)f2bf(f2.w) << 16);
    qb.z = (u32)f2bf(f3.x) | ((u32)f2bf(f3.y) << 16);
    qb.w = (u32)f2bf(f3.z) | ((u32)f2bf(f3.w) << 16);
    *(uint4*)&W0[o * 72 + c0] = qa;
    *(uint4*)&W0[o * 72 + c0 + 8] = qb;
    if (side) {
      const float4* v4 = (const float4*)(wv + o * 64 + c0);
      float4 g0 = v4[0], g1 = v4[1], g2 = v4[2], g3 = v4[3];
      qa.x = (u32)f2bf(g0.x) | ((u32)f2bf(g0.y) << 16);
      qa.y = (u32)f2bf(g0.z) | ((u32)f2bf(g0.w) << 16);
      qa.z = (u32)f2bf(g1.x) | ((u32)f2bf(g1.y) << 16);
      qa.w = (u32)f2bf(g1.z) | ((u32)f2bf(g1.w) << 16);
      qb.x = (u32)f2bf(g2.x) | ((u32)f2bf(g2.y) << 16);
      qb.y = (u32)f2bf(g2.z) | ((u32)f2bf(g2.w) << 16);
      qb.z = (u32)f2bf(g3.x) | ((u32)f2bf(g3.y) << 16);
      qb.w = (u32)f2bf(g3.z) | ((u32)f2bf(g3.w) << 16);
      *(uint4*)&W1[o * 72 + c0] = qa;
      *(uint4*)&W1[o * 72 + c0 + 8] = qb;
    }
  }
  __syncthreads();

  const int lane = t & 63, w = t >> 6;
  const int l15 = lane & 15, qd = lane >> 4;
  const int tb = w * 16;                  // wave's 16 tokens

  bf16x8 af0 = *(const bf16x8*)&X[(tb + l15) * 72 + qd * 8];
  bf16x8 af1 = *(const bf16x8*)&X[(tb + l15) * 72 + 32 + qd * 8];

  // ---- Q (side 0) / K (side 1): A = X (rows tok), B = W0 (cols o) ----
  f32x4 acc[4];
#pragma unroll
  for (int nt = 0; nt < 4; ++nt) {
    bf16x8 b0 = *(const bf16x8*)&W0[(nt * 16 + l15) * 72 + qd * 8];
    bf16x8 b1 = *(const bf16x8*)&W0[(nt * 16 + l15) * 72 + 32 + qd * 8];
    f32x4 a = {0.f, 0.f, 0.f, 0.f};
    a = __builtin_amdgcn_mfma_f32_16x16x32_bf16(af0, b0, a, 0, 0, 0);
    a = __builtin_amdgcn_mfma_f32_16x16x32_bf16(af1, b1, a, 0, 0, 0);
    acc[nt] = a;
  }
  {
    const float* bias0 = side ? bk : bq;
    // Q scale = hid^-0.5 * log2(e); K unscaled
    const float sc = side ? 1.f : 0.18033688f;
    u16* dst0 = side ? Ko : Qo;
#pragma unroll
    for (int nt = 0; nt < 4; ++nt) {
      float bia = bias0[nt * 16 + l15];
#pragma unroll
      for (int e = 0; e < 4; ++e) {
        int tok = idx0 + tb + qd * 4 + e;     // D row = token
        dst0[(size_t)tok * 64 + nt * 16 + l15] = f2bf((acc[nt][e] + bia) * sc);
      }
    }
  }

  if (side) {
    // ---- V: A = Wv (rows c), B = X (cols tok) -> D = V^T directly ----
    f32x4 accv[4];
#pragma unroll
    for (int ct = 0; ct < 4; ++ct) {
      bf16x8 a0 = *(const bf16x8*)&W1[(ct * 16 + l15) * 72 + qd * 8];
      bf16x8 a1 = *(const bf16x8*)&W1[(ct * 16 + l15) * 72 + 32 + qd * 8];
      f32x4 a = {0.f, 0.f, 0.f, 0.f};
      a = __builtin_amdgcn_mfma_f32_16x16x32_bf16(a0, af0, a, 0, 0, 0);
      a = __builtin_amdgcn_mfma_f32_16x16x32_bf16(a1, af1, a, 0, 0, 0);
      accv[ct] = a;
    }
#pragma unroll
    for (int ct = 0; ct < 4; ++ct) {
#pragma unroll
      for (int e = 0; e < 4; ++e) {
        int c = ct * 16 + qd * 4 + e;          // D row = V channel
        float v = accv[ct][e] + bv[c];
        Vo[((size_t)(bb * 64 + c)) * 4096 + n0 + tb + l15] = f2bf(v);
      }
    }
  }
}

// ---------------------------------------------------------------------------
// Kernel 2: attention + fused output-conv/BN epilogue, barrier-free K-loop.
// grid (8 b, 128 qtile) x 256 threads = 4 independent waves.
// Register/occupancy model (r0-r5, m69): per-SIMD reg file = 512; waves/SIMD
// = 512/total-regs (arch+acc, unified); launch_bounds arg2 caps at 512/arg2.
//   r0: batched loads, 2 waves/SIMD, 74us (ILP, no TLP)
//   r5: serialized loads @56 regs, 4 waves/SIMD, 126us (TLP, no ILP) --
//       per-tile L2 round-trips went 2 batched -> 8 serialized; net 1.7x WORSE.
// Optimum = batched ILP x max waves the file allows: live ~110 arch + 32 acc
// = ~145 total -> 3 waves/SIMD (cap 168 via launch_bounds(256,3)).
// 32-q blocks keep LDS at 32.8KB so LDS doesn't cap blocks/CU (r0's 56KB did).
// Wave w = key-split w (keys w*1024..+1024, 16 tiles of 64), all 32 block-q.
// K,V loaded batched per tile (8+8 dwordx4 in flight), direct from global
// (L2-resident). No-max softmax (exp2; log2e folded into Q scale); partials
// combine additively. Epilogue: combine 4 partials + normalize Z in LDS,
// then Y = BNaffine(Wo.Z) via MFMA, store Ya[b][n][64] bf16. Conv/BN commute
// with the bilinear resize — LeakyReLU applied post-interp in k_out.
// ---------------------------------------------------------------------------
__global__ __launch_bounds__(256, 3) void k_attn(
    const u16* __restrict__ Qg, const u16* __restrict__ Kg,
    const u16* __restrict__ Vg,
    const float* __restrict__ wo, const float* __restrict__ bo,
    const float* __restrict__ gam, const float* __restrict__ bet,
    const float* __restrict__ mean, const float* __restrict__ var,
    u16* __restrict__ Ya)
{
  __shared__ __align__(16) u16 Pb[4 * 2304];   // per-wave [32 q][72] P / partial-Z
  __shared__ __align__(16) u16 Wl[4608];       // Wo [64 o][72]
  __shared__ __align__(16) u16 Zc[2304];       // combined Z [32 q][72]
  __shared__ float lb[128];                    // [wave][32 q] denominators

  const int b  = blockIdx.x;                   // batch -> XCD affinity
  const int q0 = blockIdx.y * 32;
  const int t  = threadIdx.x;
  const int lane = t & 63, w = t >> 6;         // w = key-split 0..3
  const int l15 = lane & 15, qd = lane >> 4;
  u16* P = Pb + w * 2304;

  // ---- stage Wo (bf16, rounded) for the epilogue GEMM ----
  {
    const int o = t >> 2, c0 = (t & 3) << 4;
    const float4* p4 = (const float4*)(wo + o * 64 + c0);
    float4 f0 = p4[0], f1 = p4[1], f2 = p4[2], f3 = p4[3];
    uint4 qa, qb;
    qa.x = (u32)f2bf(f0.x) | ((u32)f2bf(f0.y) << 16);
    qa.y = (u32)f2bf(f0.z) | ((u32)f2bf(f0.w) << 16);
    qa.z = (u32)f2bf(f1.x) | ((u32)f2bf(f1.y) << 16);
    qa.w = (u32)f2bf(f1.z) | ((u32)f2bf(f1.w) << 16);
    qb.x = (u32)f2bf(f2.x) | ((u32)f2bf(f2.y) << 16);
    qb.y = (u32)f2bf(f2.z) | ((u32)f2bf(f2.w) << 16);
    qb.z = (u32)f2bf(f3.x) | ((u32)f2bf(f3.y) << 16);
    qb.w = (u32)f2bf(f3.z) | ((u32)f2bf(f3.w) << 16);
    *(uint4*)&Wl[o * 72 + c0] = qa;
    *(uint4*)&Wl[o * 72 + c0 + 8] = qb;
  }

  // ---- Q fragments (B-operand, scale*log2e pre-folded): 2 q-tiles ----
  bf16x8 qf[2][2];
#pragma unroll
  for (int qt = 0; qt < 2; ++qt) {
    const u16* p = Qg + ((size_t)(b * 4096 + q0 + qt * 16 + l15)) * 64 + qd * 8;
    qf[qt][0] = *(const bf16x8*)p;
    qf[qt][1] = *(const bf16x8*)(p + 32);
  }

  f32x4 zacc[4][2];                            // [ct][qt]
#pragma unroll
  for (int i = 0; i < 4; ++i)
#pragma unroll
    for (int j = 0; j < 2; ++j) {
      f32x4 z = {0.f, 0.f, 0.f, 0.f};
      zacc[i][j] = z;
    }
  float lacc[2] = {0.f, 0.f};

  for (int tile = 0; tile < 16; ++tile) {
    const int nn = w * 1024 + tile * 64;

    // ---- batched K loads: 8 dwordx4 in flight (ILP latency hiding) ----
    bf16x8 kf[4][2];
#pragma unroll
    for (int mt = 0; mt < 4; ++mt) {
      const u16* p = Kg + ((size_t)(b * 4096 + nn + mt * 16 + l15)) * 64 + qd * 8;
      kf[mt][0] = *(const bf16x8*)p;
      kf[mt][1] = *(const bf16x8*)(p + 32);
    }

    // ---- S^T = K·Q^T, exp2, pack P[q][key] (perm-truncated bf16) ----
#pragma unroll
    for (int qt = 0; qt < 2; ++qt) {
#pragma unroll
      for (int mt = 0; mt < 4; ++mt) {
        f32x4 a = {0.f, 0.f, 0.f, 0.f};
        a = __builtin_amdgcn_mfma_f32_16x16x32_bf16(kf[mt][0], qf[qt][0], a, 0, 0, 0);
        a = __builtin_amdgcn_mfma_f32_16x16x32_bf16(kf[mt][1], qf[qt][1], a, 0, 0, 0);
        float p0 = __builtin_amdgcn_exp2f(a[0]);
        float p1 = __builtin_amdgcn_exp2f(a[1]);
        float p2 = __builtin_amdgcn_exp2f(a[2]);
        float p3 = __builtin_amdgcn_exp2f(a[3]);
        lacc[qt] += (p0 + p1) + (p2 + p3);
        uint2 pw;
        pw.x = packhi(p0, p1);
        pw.y = packhi(p2, p3);
        *(uint2*)&P[(qt * 16 + l15) * 72 + mt * 16 + qd * 4] = pw;
      }
    }

    // ---- batched V loads (hidden under exp/pack + other waves) ----
    bf16x8 vf[4][2];
#pragma unroll
    for (int ct = 0; ct < 4; ++ct) {
      const u16* p = Vg + ((size_t)(b * 64 + ct * 16 + l15)) * 4096 + nn + qd * 8;
      vf[ct][0] = *(const bf16x8*)p;
      vf[ct][1] = *(const bf16x8*)(p + 32);
    }

    // ---- Z^T += V^T · P^T ----
#pragma unroll
    for (int qt = 0; qt < 2; ++qt) {
      bf16x8 pf0 = *(const bf16x8*)&P[(qt * 16 + l15) * 72 + qd * 8];
      bf16x8 pf1 = *(const bf16x8*)&P[(qt * 16 + l15) * 72 + 32 + qd * 8];
#pragma unroll
      for (int ct = 0; ct < 4; ++ct) {
        zacc[ct][qt] = __builtin_amdgcn_mfma_f32_16x16x32_bf16(vf[ct][0], pf0, zacc[ct][qt], 0, 0, 0);
        zacc[ct][qt] = __builtin_amdgcn_mfma_f32_16x16x32_bf16(vf[ct][1], pf1, zacc[ct][qt], 0, 0, 0);
      }
    }
  }

  // ---- epilogue: denominators + unnormalized partial Z ([q][c] bf16) ----
#pragma unroll
  for (int qt = 0; qt < 2; ++qt) {
    float l = lacc[qt];
    l += __shfl_xor(l, 16);
    l += __shfl_xor(l, 32);
    lb[w * 32 + qt * 16 + l15] = l;   // all quads write same value: benign
  }
#pragma unroll
  for (int qt = 0; qt < 2; ++qt)
#pragma unroll
    for (int ct = 0; ct < 4; ++ct) {
      uint2 pw;
      pw.x = packhi(zacc[ct][qt][0], zacc[ct][qt][1]);
      pw.y = packhi(zacc[ct][qt][2], zacc[ct][qt][3]);
      *(uint2*)&P[(qt * 16 + l15) * 72 + ct * 16 + qd * 4] = pw;
    }
  __syncthreads();

  // ---- combine 4 key-splits + normalize -> Zc[q][72] bf16 ----
  {
    const u32* Pu = (const u32*)Pb;            // wave stride 1152 u32, row 36
    u32* Zu = (u32*)Zc;
#pragma unroll
    for (int i = 0; i < 4; ++i) {
      int cell = i * 256 + t;                  // 0..1023
      int q = cell >> 5, cu = cell & 31;       // q 0..31, u32 col 0..31
      float s0 = 0.f, s1 = 0.f;
      float den = 0.f;
#pragma unroll
      for (int ww = 0; ww < 4; ++ww) {
        u32 v = Pu[ww * 1152 + q * 36 + cu];
        s0 += bflo(v);
        s1 += bfhi(v);
        den += lb[ww * 32 + q];
      }
      float inv = 1.f / den;
      Zu[q * 36 + cu] = packhi(s0 * inv, s1 * inv);
    }
  }
  __syncthreads();

  // ---- Y = affine(Wo · Z): wave w -> q rows (w&1)*16..+15, o-half w>>1 ----
  {
    const int qr = w & 1, oh = w >> 1;
    bf16x8 af0 = *(const bf16x8*)&Zc[(qr * 16 + l15) * 72 + qd * 8];
    bf16x8 af1 = *(const bf16x8*)&Zc[(qr * 16 + l15) * 72 + 32 + qd * 8];
#pragma unroll
    for (int ni = 0; ni < 2; ++ni) {
      const int nt = oh * 2 + ni;
      bf16x8 b0 = *(const bf16x8*)&Wl[(nt * 16 + l15) * 72 + qd * 8];
      bf16x8 b1 = *(const bf16x8*)&Wl[(nt * 16 + l15) * 72 + 32 + qd * 8];
      f32x4 y = {0.f, 0.f, 0.f, 0.f};
      y = __builtin_amdgcn_mfma_f32_16x16x32_bf16(af0, b0, y, 0, 0, 0);
      y = __builtin_amdgcn_mfma_f32_16x16x32_bf16(af1, b1, y, 0, 0, 0);
      const int o = nt * 16 + l15;
      float A = gam[o] * __frsqrt_rn(var[o] + 1e-5f);
      float B = (bo[o] - mean[o]) * A + bet[o];
#pragma unroll
      for (int e = 0; e < 4; ++e) {
        float v = y[e] * A + B;
        size_t tok = (size_t)(b * 4096 + q0 + qr * 16 + qd * 4 + e);
        Ya[tok * 64 + o] = (u16)(__float_as_uint(v) >> 16);
      }
    }
  }
}

// ---------------------------------------------------------------------------
// Kernel 3: bilinear 2x upsample of Ya + LeakyReLU + residual.
// grid 1024 x 256: thread = one (b,i,j,channel-half) — 2 threads/pixel,
// 32 channels each -> 4 blocks/CU = 4 waves/SIMD for latency hiding.
// Ya is channel-innermost -> each corner read is a contiguous 64 B run.
// ---------------------------------------------------------------------------
__global__ __launch_bounds__(256, 4) void k_out(
    const u16* __restrict__ Ya, const float* __restrict__ rgb,
    float* __restrict__ out)
{
  const int tid = blockIdx.x * 256 + threadIdx.x;  // 0..262143
  const int cg  = tid & 1;                         // channel half (o = cg*32..)
  const int px  = tid >> 1;                        // 0..131071
  const int j = px & 127;
  const int i = (px >> 7) & 127;
  const int b = px >> 14;

  float ys = fmaxf((i + 0.5f) * 0.5f - 0.5f, 0.f);
  int   y0 = (int)ys;
  float wy = ys - (float)y0;
  int   y1 = min(y0 + 1, 63);
  float xs = fmaxf((j + 0.5f) * 0.5f - 0.5f, 0.f);
  int   x0 = (int)xs;
  float wx = xs - (float)x0;
  int   x1 = min(x0 + 1, 63);
  float w00 = (1.f - wy) * (1.f - wx), w01 = (1.f - wy) * wx;
  float w10 = wy * (1.f - wx),         w11 = wy * wx;

  const u16* yb = Ya + (size_t)b * 262144;
  const int b00 = (y0 * 64 + x0) * 64, b01 = (y0 * 64 + x1) * 64;
  const int b10 = (y1 * 64 + x0) * 64, b11 = (y1 * 64 + x1) * 64;
  const int ch0 = cg * 4;                          // uint4-granule base

#pragma unroll
  for (int ch = 0; ch < 4; ++ch) {
    const int cc = ch0 + ch;
    uint4 a00 = *(const uint4*)&yb[b00 + cc * 8];
    uint4 a01 = *(const uint4*)&yb[b01 + cc * 8];
    uint4 a10 = *(const uint4*)&yb[b10 + cc * 8];
    uint4 a11 = *(const uint4*)&yb[b11 + cc * 8];
    const u32* u00 = (const u32*)&a00;
    const u32* u01 = (const u32*)&a01;
    const u32* u10 = (const u32*)&a10;
    const u32* u11 = (const u32*)&a11;
#pragma unroll
    for (int e = 0; e < 8; ++e) {
      const int wd = e >> 1;
      float c00 = (e & 1) ? bfhi(u00[wd]) : bflo(u00[wd]);
      float c01 = (e & 1) ? bfhi(u01[wd]) : bflo(u01[wd]);
      float c10 = (e & 1) ? bfhi(u10[wd]) : bflo(u10[wd]);
      float c11 = (e & 1) ? bfhi(u11[wd]) : bflo(u11[wd]);
      float v = w00 * c00 + w01 * c01 + w10 * c10 + w11 * c11;
      v = (v >= 0.f) ? v : 0.2f * v;
      const int o = cc * 8 + e;
      const size_t oi = ((size_t)((b * 64 + o) * 128 + i)) * 128 + j;
      out[oi] = rgb[oi] + v;
    }
  }
}

// ---------------------------------------------------------------------------
extern "C" void kernel_launch(void* const* d_in, const int* in_sizes, int n_in,
                              void* d_out, int out_size, void* d_ws, size_t ws_size,
                              hipStream_t stream) {
  (void)in_sizes; (void)n_in; (void)out_size; (void)ws_size;
  const float* rgb  = (const float*)d_in[0];
  const float* freq = (const float*)d_in[1];
  const float* wq   = (const float*)d_in[2];
  const float* bq   = (const float*)d_in[3];
  const float* wk   = (const float*)d_in[4];
  const float* bk   = (const float*)d_in[5];
  const float* wv   = (const float*)d_in[6];
  const float* bv   = (const float*)d_in[7];
  const float* wo   = (const float*)d_in[8];
  const float* bo   = (const float*)d_in[9];
  const float* gam  = (const float*)d_in[10];
  const float* bet  = (const float*)d_in[11];
  const float* mean = (const float*)d_in[12];
  const float* var  = (const float*)d_in[13];

  char* ws = (char*)d_ws;
  u16* Qw = (u16*)(ws);               // 8*4096*64 bf16 = 4 MiB
  u16* Kw = (u16*)(ws + 4194304);     // 4 MiB
  u16* Vw = (u16*)(ws + 8388608);     // 4 MiB (transposed [b][c][n])
  u16* Yw = (u16*)(ws + 12582912);    // 4 MiB  Ya[b][n][64] bf16

  k_qkv<<<dim3(1024), dim3(256), 0, stream>>>(rgb, freq, wq, bq, wk, bk, wv, bv,
                                              Qw, Kw, Vw);
  k_attn<<<dim3(8, 128), dim3(256), 0, stream>>>(Qw, Kw, Vw, wo, bo, gam, bet,
                                                 mean, var, Yw);
  k_out<<<dim3(1024), dim3(256), 0, stream>>>(Yw, rgb, (float*)d_out);
}

// Round 7
// 204.233 us; speedup vs baseline: 1.4080x; 1.2602x over previous
//
#include <hip/hip_runtime.h>
#include <hip/hip_bf16.h>

typedef unsigned short u16;
typedef unsigned int   u32;
typedef __attribute__((ext_vector_type(8))) short bf16x8;
typedef __attribute__((ext_vector_type(4))) float f32x4;

__device__ __forceinline__ u16 f2bf(float f) {
  u32 u = __float_as_uint(f);
  u32 r = u + 0x7fffu + ((u >> 16) & 1u);
  return (u16)(r >> 16);
}
__device__ __forceinline__ float bflo(u32 u) { return __uint_as_float(u << 16); }
__device__ __forceinline__ float bfhi(u32 u) { return __uint_as_float(u & 0xffff0000u); }
// pack (hi16(b)<<16)|hi16(a) in one v_perm (truncation-to-bf16; bias cancels
// in softmax normalization, ~0.4% rel elsewhere — noise vs 0.109 threshold)
__device__ __forceinline__ u32 packhi(float a, float b) {
  return __builtin_amdgcn_perm(__float_as_uint(b), __float_as_uint(a), 0x07060302u);
}

// ---------------------------------------------------------------------------
// Kernel 1: avgpool 2x2 + Q/K/V 1x1-conv projections via MFMA.
// grid 1024 x 256 (4 waves). side = blockIdx&1 (0: rgb->Q, 1: freq->K,V).
// Q,K stored [b][n][64] bf16; V stored [b][64][n] bf16.
// Q pre-scaled by hid^-0.5 * log2(e) = 0.125*1.4426950 so k_attn can use
// exp2 directly (saves one v_mul per softmax element).
// ---------------------------------------------------------------------------
__global__ __launch_bounds__(256, 4) void k_qkv(
    const float* __restrict__ rgb, const float* __restrict__ freq,
    const float* __restrict__ wq, const float* __restrict__ bq,
    const float* __restrict__ wk, const float* __restrict__ bk,
    const float* __restrict__ wv, const float* __restrict__ bv,
    u16* __restrict__ Qo, u16* __restrict__ Ko, u16* __restrict__ Vo)
{
  __shared__ __align__(16) u16 sm[3 * 4608];
  u16* X  = sm;             // [64][72] pooled input tokens
  u16* W0 = sm + 4608;      // [64][72] wq or wk
  u16* W1 = sm + 9216;      // [64][72] wv (side 1 only)

  const int t    = threadIdx.x;
  const int side = blockIdx.x & 1;
  const int seg  = blockIdx.x >> 1;       // 0..511
  const int idx0 = seg * 64;              // global token base (b*4096+n)
  const int bb   = idx0 >> 12;
  const int n0   = idx0 & 4095;
  const int h    = n0 >> 6;               // pooled row (uniform per block)
  const float* src = side ? freq : rgb;

  // ---- stage pooled X: 64 tokens (one pooled row) x 64 ch ----
  const size_t sbase = (size_t)bb * 64 * 16384 + (size_t)(2 * h) * 128;
  for (int i = 0; i < 2; ++i) {
    int cell = i * 256 + t;               // 0..511
    int tok  = cell & 63;                 // lane-consecutive -> coalesced
    int grp  = cell >> 6;                 // channel granule 0..7
    const float* p0 = src + sbase + 2 * tok + (size_t)(grp * 8) * 16384;
    u32 pk[4];
#pragma unroll
    for (int cc = 0; cc < 8; cc += 2) {
      const float* pa = p0 + (size_t)cc * 16384;
      float2 a0 = *(const float2*)pa;
      float2 a1 = *(const float2*)(pa + 128);
      float v0 = 0.25f * ((a0.x + a0.y) + (a1.x + a1.y));
      const float* pb = pa + 16384;
      float2 b0 = *(const float2*)pb;
      float2 b1 = *(const float2*)(pb + 128);
      float v1 = 0.25f * ((b0.x + b0.y) + (b1.x + b1.y));
      pk[cc >> 1] = (u32)f2bf(v0) | ((u32)f2bf(v1) << 16);
    }
    uint4 q4; q4.x = pk[0]; q4.y = pk[1]; q4.z = pk[2]; q4.w = pk[3];
    *(uint4*)&X[tok * 72 + grp * 8] = q4;
  }
  // ---- stage weights, float4-coalesced: thread -> (o = t>>2, c0 = (t&3)*16)
  {
    const int o = t >> 2, c0 = (t & 3) << 4;
    const float4* p4 = (const float4*)((side ? wk : wq) + o * 64 + c0);
    float4 f0 = p4[0], f1 = p4[1], f2 = p4[2], f3 = p4[3];
    uint4 qa, qb;
    qa.x = (u32)f2bf(f0.x) | ((u32)f2bf(f0.y) << 16);
    qa.y = (u32)f2bf(f0.z) | ((u32)f2bf(f0.w) << 16);
    qa.z = (u32)f2bf(f1.x) | ((u32)f2bf(f1.y) << 16);
    qa.w = (u32)f2bf(f1.z) | ((u32)f2bf(f1.w) << 16);
    qb.x = (u32)f2bf(f2.x) | ((u32)f2bf(f2.y) << 16);
    qb.y = (u32)f2bf(f2.z) | ((u32)f2bf(f2.w) << 16);
    qb.z = (u32)f2bf(f3.x) | ((u32)f2bf(f3.y) << 16);
    qb.w = (u32)f2bf(f3.z) | ((u32)f2bf(f3.w) << 16);
    *(uint4*)&W0[o * 72 + c0] = qa;
    *(uint4*)&W0[o * 72 + c0 + 8] = qb;
    if (side) {
      const float4* v4 = (const float4*)(wv + o * 64 + c0);
      float4 g0 = v4[0], g1 = v4[1], g2 = v4[2], g3 = v4[3];
      qa.x = (u32)f2bf(g0.x) | ((u32)f2bf(g0.y) << 16);
      qa.y = (u32)f2bf(g0.z) | ((u32)f2bf(g0.w) << 16);
      qa.z = (u32)f2bf(g1.x) | ((u32)f2bf(g1.y) << 16);
      qa.w = (u32)f2bf(g1.z) | ((u32)f2bf(g1.w) << 16);
      qb.x = (u32)f2bf(g2.x) | ((u32)f2bf(g2.y) << 16);
      qb.y = (u32)f2bf(g2.z) | ((u32)f2bf(g2.w) << 16);
      qb.z = (u32)f2bf(g3.x) | ((u32)f2bf(g3.y) << 16);
      qb.w = (u32)f2bf(g3.z) | ((u32)f2bf(g3.w) << 16);
      *(uint4*)&W1[o * 72 + c0] = qa;
      *(uint4*)&W1[o * 72 + c0 + 8] = qb;
    }
  }
  __syncthreads();

  const int lane = t & 63, w = t >> 6;
  const int l15 = lane & 15, qd = lane >> 4;
  const int tb = w * 16;                  // wave's 16 tokens

  bf16x8 af0 = *(const bf16x8*)&X[(tb + l15) * 72 + qd * 8];
  bf16x8 af1 = *(const bf16x8*)&X[(tb + l15) * 72 + 32 + qd * 8];

  // ---- Q (side 0) / K (side 1): A = X (rows tok), B = W0 (cols o) ----
  f32x4 acc[4];
#pragma unroll
  for (int nt = 0; nt < 4; ++nt) {
    bf16x8 b0 = *(const bf16x8*)&W0[(nt * 16 + l15) * 72 + qd * 8];
    bf16x8 b1 = *(const bf16x8*)&W0[(nt * 16 + l15) * 72 + 32 + qd * 8];
    f32x4 a = {0.f, 0.f, 0.f, 0.f};
    a = __builtin_amdgcn_mfma_f32_16x16x32_bf16(af0, b0, a, 0, 0, 0);
    a = __builtin_amdgcn_mfma_f32_16x16x32_bf16(af1, b1, a, 0, 0, 0);
    acc[nt] = a;
  }
  {
    const float* bias0 = side ? bk : bq;
    // Q scale = hid^-0.5 * log2(e); K unscaled
    const float sc = side ? 1.f : 0.18033688f;
    u16* dst0 = side ? Ko : Qo;
#pragma unroll
    for (int nt = 0; nt < 4; ++nt) {
      float bia = bias0[nt * 16 + l15];
#pragma unroll
      for (int e = 0; e < 4; ++e) {
        int tok = idx0 + tb + qd * 4 + e;     // D row = token
        dst0[(size_t)tok * 64 + nt * 16 + l15] = f2bf((acc[nt][e] + bia) * sc);
      }
    }
  }

  if (side) {
    // ---- V: A = Wv (rows c), B = X (cols tok) -> D = V^T directly ----
    f32x4 accv[4];
#pragma unroll
    for (int ct = 0; ct < 4; ++ct) {
      bf16x8 a0 = *(const bf16x8*)&W1[(ct * 16 + l15) * 72 + qd * 8];
      bf16x8 a1 = *(const bf16x8*)&W1[(ct * 16 + l15) * 72 + 32 + qd * 8];
      f32x4 a = {0.f, 0.f, 0.f, 0.f};
      a = __builtin_amdgcn_mfma_f32_16x16x32_bf16(a0, af0, a, 0, 0, 0);
      a = __builtin_amdgcn_mfma_f32_16x16x32_bf16(a1, af1, a, 0, 0, 0);
      accv[ct] = a;
    }
#pragma unroll
    for (int ct = 0; ct < 4; ++ct) {
#pragma unroll
      for (int e = 0; e < 4; ++e) {
        int c = ct * 16 + qd * 4 + e;          // D row = V channel
        float v = accv[ct][e] + bv[c];
        Vo[((size_t)(bb * 64 + c)) * 4096 + n0 + tb + l15] = f2bf(v);
      }
    }
  }
}

// ---------------------------------------------------------------------------
// Kernel 2: attention + fused output-conv/BN epilogue, barrier-free K-loop.
// grid (8 b, 64 qtile) x 256 threads = 4 independent waves.
// CONSOLIDATED to the round-0 structure — the verified optimum of this design
// family after 6 rounds of occupancy/ILP exploration:
//   r0: 64-q blocks, (256,2), batched loads -> VGPR 128, 74us  (BEST)
//   r1/r3: reg double-buffer / 512-thr -> spill (95/133us)
//   r5: serialized loads @56 regs, 4 waves/SIMD -> 126us (TLP < ILP here)
//   r6: batched-intent @32-q tile -> compiler sank loads anyway (72 regs, 129us)
// Lesson: only the LARGE tile (4 q-tiles, 64 acc regs) makes the scheduler
// keep the batched 16-load/tile codegen. Do not shrink the tile again.
// Deltas vs r0 (both minimal-risk, no regalloc impact):
//   - exp2 instead of __expf (log2e pre-folded into Q by k_qkv)
//   - s_setprio(1) around MFMA clusters (T5: attn-proven +4-7%, m191)
// Wave w: key-split w (keys w*1024..+1024, 16 tiles of 64), all 64 block-q.
// K,V frags direct from global (L2-resident per XCD: 1 MB/batch).
// No-max softmax; partials combine additively. Epilogue: combine+normalize
// Z in LDS (bf16), then Y = BNaffine(Wo·Z) via MFMA, store Ya[b][n][64] bf16.
// Conv/BN commute with the bilinear resize — LeakyReLU applied in k_out.
// ---------------------------------------------------------------------------
__global__ __launch_bounds__(256, 2) void k_attn(
    const u16* __restrict__ Qg, const u16* __restrict__ Kg,
    const u16* __restrict__ Vg,
    const float* __restrict__ wo, const float* __restrict__ bo,
    const float* __restrict__ gam, const float* __restrict__ bet,
    const float* __restrict__ mean, const float* __restrict__ var,
    u16* __restrict__ Ya)
{
  __shared__ __align__(16) u16 Pb[4 * 4608];   // per-wave [64 q][72] P / partial-Z
  __shared__ __align__(16) u16 Wl[4608];       // Wo [64 o][72]
  __shared__ __align__(16) u16 Zc[4608];       // combined Z [64 q][72]
  __shared__ float lb[256];                    // [wave][64 q] denominators

  const int b  = blockIdx.x;                   // batch -> XCD affinity
  const int q0 = blockIdx.y * 64;
  const int t  = threadIdx.x;
  const int lane = t & 63, w = t >> 6;
  const int l15 = lane & 15, qd = lane >> 4;
  u16* P = Pb + w * 4608;

  // ---- stage Wo (bf16, rounded) for the epilogue GEMM ----
  {
    const int o = t >> 2, c0 = (t & 3) << 4;
    const float4* p4 = (const float4*)(wo + o * 64 + c0);
    float4 f0 = p4[0], f1 = p4[1], f2 = p4[2], f3 = p4[3];
    uint4 qa, qb;
    qa.x = (u32)f2bf(f0.x) | ((u32)f2bf(f0.y) << 16);
    qa.y = (u32)f2bf(f0.z) | ((u32)f2bf(f0.w) << 16);
    qa.z = (u32)f2bf(f1.x) | ((u32)f2bf(f1.y) << 16);
    qa.w = (u32)f2bf(f1.z) | ((u32)f2bf(f1.w) << 16);
    qb.x = (u32)f2bf(f2.x) | ((u32)f2bf(f2.y) << 16);
    qb.y = (u32)f2bf(f2.z) | ((u32)f2bf(f2.w) << 16);
    qb.z = (u32)f2bf(f3.x) | ((u32)f2bf(f3.y) << 16);
    qb.w = (u32)f2bf(f3.z) | ((u32)f2bf(f3.w) << 16);
    *(uint4*)&Wl[o * 72 + c0] = qa;
    *(uint4*)&Wl[o * 72 + c0 + 8] = qb;
  }

  // ---- Q fragments (B-operand, scale*log2e pre-folded) ----
  bf16x8 qf[4][2];
#pragma unroll
  for (int qt = 0; qt < 4; ++qt) {
    const u16* p = Qg + ((size_t)(b * 4096 + q0 + qt * 16 + l15)) * 64 + qd * 8;
    qf[qt][0] = *(const bf16x8*)p;
    qf[qt][1] = *(const bf16x8*)(p + 32);
  }

  f32x4 zacc[4][4];                            // [ct][qt]
#pragma unroll
  for (int i = 0; i < 4; ++i)
#pragma unroll
    for (int j = 0; j < 4; ++j) {
      f32x4 z = {0.f, 0.f, 0.f, 0.f};
      zacc[i][j] = z;
    }
  float lacc[4] = {0.f, 0.f, 0.f, 0.f};

  for (int tile = 0; tile < 16; ++tile) {
    const int n0 = w * 1024 + tile * 64;

    // batch all K+V loads at tile top; other resident wave's softmax hides them
    bf16x8 kf[4][2], vf[4][2];
#pragma unroll
    for (int mt = 0; mt < 4; ++mt) {
      const u16* p = Kg + ((size_t)(b * 4096 + n0 + mt * 16 + l15)) * 64 + qd * 8;
      kf[mt][0] = *(const bf16x8*)p;
      kf[mt][1] = *(const bf16x8*)(p + 32);
    }
#pragma unroll
    for (int ct = 0; ct < 4; ++ct) {
      const u16* p = Vg + ((size_t)(b * 64 + ct * 16 + l15)) * 4096 + n0 + qd * 8;
      vf[ct][0] = *(const bf16x8*)p;
      vf[ct][1] = *(const bf16x8*)(p + 32);
    }

    // ---- S^T = K·Q^T, exp2, pack P[q][key] (perm-truncated bf16) ----
#pragma unroll
    for (int qt = 0; qt < 4; ++qt) {
#pragma unroll
      for (int mt = 0; mt < 4; ++mt) {
        f32x4 a = {0.f, 0.f, 0.f, 0.f};
        __builtin_amdgcn_s_setprio(1);
        a = __builtin_amdgcn_mfma_f32_16x16x32_bf16(kf[mt][0], qf[qt][0], a, 0, 0, 0);
        a = __builtin_amdgcn_mfma_f32_16x16x32_bf16(kf[mt][1], qf[qt][1], a, 0, 0, 0);
        __builtin_amdgcn_s_setprio(0);
        float p0 = __builtin_amdgcn_exp2f(a[0]);
        float p1 = __builtin_amdgcn_exp2f(a[1]);
        float p2 = __builtin_amdgcn_exp2f(a[2]);
        float p3 = __builtin_amdgcn_exp2f(a[3]);
        lacc[qt] += (p0 + p1) + (p2 + p3);
        uint2 pw;
        pw.x = packhi(p0, p1);
        pw.y = packhi(p2, p3);
        *(uint2*)&P[(qt * 16 + l15) * 72 + mt * 16 + qd * 4] = pw;
      }
    }
    // ---- Z^T += V^T · P^T ----
#pragma unroll
    for (int qt = 0; qt < 4; ++qt) {
      bf16x8 pf0 = *(const bf16x8*)&P[(qt * 16 + l15) * 72 + qd * 8];
      bf16x8 pf1 = *(const bf16x8*)&P[(qt * 16 + l15) * 72 + 32 + qd * 8];
      __builtin_amdgcn_s_setprio(1);
#pragma unroll
      for (int ct = 0; ct < 4; ++ct) {
        zacc[ct][qt] = __builtin_amdgcn_mfma_f32_16x16x32_bf16(vf[ct][0], pf0, zacc[ct][qt], 0, 0, 0);
        zacc[ct][qt] = __builtin_amdgcn_mfma_f32_16x16x32_bf16(vf[ct][1], pf1, zacc[ct][qt], 0, 0, 0);
      }
      __builtin_amdgcn_s_setprio(0);
    }
  }

  // ---- epilogue: denominators + unnormalized partial Z ([q][c] bf16) ----
#pragma unroll
  for (int qt = 0; qt < 4; ++qt) {
    float l = lacc[qt];
    l += __shfl_xor(l, 16);
    l += __shfl_xor(l, 32);
    lb[w * 64 + qt * 16 + l15] = l;   // all quads write same value: benign
  }
#pragma unroll
  for (int qt = 0; qt < 4; ++qt)
#pragma unroll
    for (int ct = 0; ct < 4; ++ct) {
      uint2 pw;
      pw.x = packhi(zacc[ct][qt][0], zacc[ct][qt][1]);
      pw.y = packhi(zacc[ct][qt][2], zacc[ct][qt][3]);
      *(uint2*)&P[(qt * 16 + l15) * 72 + ct * 16 + qd * 4] = pw;
    }
  __syncthreads();

  // ---- combine 4 key-splits + normalize -> Zc[q][72] bf16 ----
  {
    const u32* Pu = (const u32*)Pb;            // wave stride 2304 u32, row 36
    u32* Zu = (u32*)Zc;
#pragma unroll
    for (int i = 0; i < 8; ++i) {
      int cell = i * 256 + t;                  // 0..2047
      int q = cell >> 5, cu = cell & 31;
      float s0 = 0.f, s1 = 0.f;
#pragma unroll
      for (int ww = 0; ww < 4; ++ww) {
        u32 v = Pu[ww * 2304 + q * 36 + cu];
        s0 += bflo(v);
        s1 += bfhi(v);
      }
      float inv = 1.f / (lb[q] + lb[64 + q] + lb[128 + q] + lb[192 + q]);
      Zu[q * 36 + cu] = packhi(s0 * inv, s1 * inv);
    }
  }
  __syncthreads();

  // ---- Y = affine(Wo · Z): wave w handles q rows w*16..+15, all 64 o ----
  {
    bf16x8 af0 = *(const bf16x8*)&Zc[(w * 16 + l15) * 72 + qd * 8];
    bf16x8 af1 = *(const bf16x8*)&Zc[(w * 16 + l15) * 72 + 32 + qd * 8];
#pragma unroll
    for (int nt = 0; nt < 4; ++nt) {
      bf16x8 b0 = *(const bf16x8*)&Wl[(nt * 16 + l15) * 72 + qd * 8];
      bf16x8 b1 = *(const bf16x8*)&Wl[(nt * 16 + l15) * 72 + 32 + qd * 8];
      f32x4 y = {0.f, 0.f, 0.f, 0.f};
      y = __builtin_amdgcn_mfma_f32_16x16x32_bf16(af0, b0, y, 0, 0, 0);
      y = __builtin_amdgcn_mfma_f32_16x16x32_bf16(af1, b1, y, 0, 0, 0);
      const int o = nt * 16 + l15;
      float A = gam[o] * __frsqrt_rn(var[o] + 1e-5f);
      float B = (bo[o] - mean[o]) * A + bet[o];
#pragma unroll
      for (int e = 0; e < 4; ++e) {
        float v = y[e] * A + B;
        size_t tok = (size_t)(b * 4096 + q0 + w * 16 + qd * 4 + e);
        Ya[tok * 64 + o] = (u16)(__float_as_uint(v) >> 16);
      }
    }
  }
}

// ---------------------------------------------------------------------------
// Kernel 3: bilinear 2x upsample of Ya + LeakyReLU + residual.
// grid 1024 x 256: thread = one (b,i,j,channel-half) — 2 threads/pixel,
// 32 channels each -> 4 blocks/CU = 4 waves/SIMD for latency hiding.
// Ya is channel-innermost -> each corner read is a contiguous 64 B run.
// ---------------------------------------------------------------------------
__global__ __launch_bounds__(256, 4) void k_out(
    const u16* __restrict__ Ya, const float* __restrict__ rgb,
    float* __restrict__ out)
{
  const int tid = blockIdx.x * 256 + threadIdx.x;  // 0..262143
  const int cg  = tid & 1;                         // channel half (o = cg*32..)
  const int px  = tid >> 1;                        // 0..131071
  const int j = px & 127;
  const int i = (px >> 7) & 127;
  const int b = px >> 14;

  float ys = fmaxf((i + 0.5f) * 0.5f - 0.5f, 0.f);
  int   y0 = (int)ys;
  float wy = ys - (float)y0;
  int   y1 = min(y0 + 1, 63);
  float xs = fmaxf((j + 0.5f) * 0.5f - 0.5f, 0.f);
  int   x0 = (int)xs;
  float wx = xs - (float)x0;
  int   x1 = min(x0 + 1, 63);
  float w00 = (1.f - wy) * (1.f - wx), w01 = (1.f - wy) * wx;
  float w10 = wy * (1.f - wx),         w11 = wy * wx;

  const u16* yb = Ya + (size_t)b * 262144;
  const int b00 = (y0 * 64 + x0) * 64, b01 = (y0 * 64 + x1) * 64;
  const int b10 = (y1 * 64 + x0) * 64, b11 = (y1 * 64 + x1) * 64;
  const int ch0 = cg * 4;                          // uint4-granule base

#pragma unroll
  for (int ch = 0; ch < 4; ++ch) {
    const int cc = ch0 + ch;
    uint4 a00 = *(const uint4*)&yb[b00 + cc * 8];
    uint4 a01 = *(const uint4*)&yb[b01 + cc * 8];
    uint4 a10 = *(const uint4*)&yb[b10 + cc * 8];
    uint4 a11 = *(const uint4*)&yb[b11 + cc * 8];
    const u32* u00 = (const u32*)&a00;
    const u32* u01 = (const u32*)&a01;
    const u32* u10 = (const u32*)&a10;
    const u32* u11 = (const u32*)&a11;
#pragma unroll
    for (int e = 0; e < 8; ++e) {
      const int wd = e >> 1;
      float c00 = (e & 1) ? bfhi(u00[wd]) : bflo(u00[wd]);
      float c01 = (e & 1) ? bfhi(u01[wd]) : bflo(u01[wd]);
      float c10 = (e & 1) ? bfhi(u10[wd]) : bflo(u10[wd]);
      float c11 = (e & 1) ? bfhi(u11[wd]) : bflo(u11[wd]);
      float v = w00 * c00 + w01 * c01 + w10 * c10 + w11 * c11;
      v = (v >= 0.f) ? v : 0.2f * v;
      const int o = cc * 8 + e;
      const size_t oi = ((size_t)((b * 64 + o) * 128 + i)) * 128 + j;
      out[oi] = rgb[oi] + v;
    }
  }
}

// ---------------------------------------------------------------------------
extern "C" void kernel_launch(void* const* d_in, const int* in_sizes, int n_in,
                              void* d_out, int out_size, void* d_ws, size_t ws_size,
                              hipStream_t stream) {
  (void)in_sizes; (void)n_in; (void)out_size; (void)ws_size;
  const float* rgb  = (const float*)d_in[0];
  const float* freq = (const float*)d_in[1];
  const float* wq   = (const float*)d_in[2];
  const float* bq   = (const float*)d_in[3];
  const float* wk   = (const float*)d_in[4];
  const float* bk   = (const float*)d_in[5];
  const float* wv   = (const float*)d_in[6];
  const float* bv   = (const float*)d_in[7];
  const float* wo   = (const float*)d_in[8];
  const float* bo   = (const float*)d_in[9];
  const float* gam  = (const float*)d_in[10];
  const float* bet  = (const float*)d_in[11];
  const float* mean = (const float*)d_in[12];
  const float* var  = (const float*)d_in[13];

  char* ws = (char*)d_ws;
  u16* Qw = (u16*)(ws);               // 8*4096*64 bf16 = 4 MiB
  u16* Kw = (u16*)(ws + 4194304);     // 4 MiB
  u16* Vw = (u16*)(ws + 8388608);     // 4 MiB (transposed [b][c][n])
  u16* Yw = (u16*)(ws + 12582912);    // 4 MiB  Ya[b][n][64] bf16

  k_qkv<<<dim3(1024), dim3(256), 0, stream>>>(rgb, freq, wq, bq, wk, bk, wv, bv,
                                              Qw, Kw, Vw);
  k_attn<<<dim3(8, 64), dim3(256), 0, stream>>>(Qw, Kw, Vw, wo, bo, gam, bet,
                                                mean, var, Yw);
  k_out<<<dim3(1024), dim3(256), 0, stream>>>(Yw, rgb, (float*)d_out);
}

// Round 8
// 201.307 us; speedup vs baseline: 1.4284x; 1.0145x over previous
//
#include <hip/hip_runtime.h>
#include <hip/hip_bf16.h>

typedef unsigned short u16;
typedef unsigned int   u32;
typedef __attribute__((ext_vector_type(8))) short bf16x8;
typedef __attribute__((ext_vector_type(4))) float f32x4;

__device__ __forceinline__ u16 f2bf(float f) {
  u32 u = __float_as_uint(f);
  u32 r = u + 0x7fffu + ((u >> 16) & 1u);
  return (u16)(r >> 16);
}
__device__ __forceinline__ float bflo(u32 u) { return __uint_as_float(u << 16); }
__device__ __forceinline__ float bfhi(u32 u) { return __uint_as_float(u & 0xffff0000u); }
// pack (hi16(b)<<16)|hi16(a) in one v_perm (truncation-to-bf16; bias cancels
// in softmax normalization, ~0.4% rel elsewhere — noise vs 0.109 threshold)
__device__ __forceinline__ u32 packhi(float a, float b) {
  return __builtin_amdgcn_perm(__float_as_uint(b), __float_as_uint(a), 0x07060302u);
}

// ---------------------------------------------------------------------------
// Kernel 1: avgpool 2x2 + Q/K/V 1x1-conv projections via MFMA.
// grid 1024 x 256 (4 waves). side = blockIdx&1 (0: rgb->Q, 1: freq->K,V).
// Q,K stored [b][n][64] bf16; V stored [b][64][n] bf16.
// Q pre-scaled by hid^-0.5 * log2(e) = 0.125*1.4426950 so k_attn can use
// exp2 directly. Staging uses float4 loads (2 pooled columns per load) —
// halves VMEM instruction count vs float2 (r7: phase was instruction-bound,
// 64MB at 8B/inst; same bytes at 16B/inst).
// ---------------------------------------------------------------------------
__global__ __launch_bounds__(256, 4) void k_qkv(
    const float* __restrict__ rgb, const float* __restrict__ freq,
    const float* __restrict__ wq, const float* __restrict__ bq,
    const float* __restrict__ wk, const float* __restrict__ bk,
    const float* __restrict__ wv, const float* __restrict__ bv,
    u16* __restrict__ Qo, u16* __restrict__ Ko, u16* __restrict__ Vo)
{
  __shared__ __align__(16) u16 sm[3 * 4608];
  u16* X  = sm;             // [64][72] pooled input tokens
  u16* W0 = sm + 4608;      // [64][72] wq or wk
  u16* W1 = sm + 9216;      // [64][72] wv (side 1 only)

  const int t    = threadIdx.x;
  const int side = blockIdx.x & 1;
  const int seg  = blockIdx.x >> 1;       // 0..511
  const int idx0 = seg * 64;              // global token base (b*4096+n)
  const int bb   = idx0 >> 12;
  const int n0   = idx0 & 4095;
  const int h    = n0 >> 6;               // pooled row (uniform per block)
  const float* src = side ? freq : rgb;

  // ---- stage pooled X: thread = (token-pair, channel-granule), float4 ----
  const size_t sbase = (size_t)bb * 64 * 16384 + (size_t)(2 * h) * 128;
  {
    const int tokp = t & 31;              // token pair 0..31 (lane-consecutive)
    const int grp  = t >> 5;              // channel granule 0..7
    const float* p0 = src + sbase + 4 * tokp + (size_t)(grp * 8) * 16384;
    u32 pk0[4], pk1[4];
#pragma unroll
    for (int c = 0; c < 8; c += 2) {
      const float* pa = p0 + (size_t)c * 16384;
      float4 a0 = *(const float4*)pa;
      float4 a1 = *(const float4*)(pa + 128);
      float t0a = 0.25f * ((a0.x + a0.y) + (a1.x + a1.y));
      float t1a = 0.25f * ((a0.z + a0.w) + (a1.z + a1.w));
      const float* pb = pa + 16384;
      float4 c0 = *(const float4*)pb;
      float4 c1 = *(const float4*)(pb + 128);
      float t0b = 0.25f * ((c0.x + c0.y) + (c1.x + c1.y));
      float t1b = 0.25f * ((c0.z + c0.w) + (c1.z + c1.w));
      pk0[c >> 1] = (u32)f2bf(t0a) | ((u32)f2bf(t0b) << 16);
      pk1[c >> 1] = (u32)f2bf(t1a) | ((u32)f2bf(t1b) << 16);
    }
    uint4 qv0; qv0.x = pk0[0]; qv0.y = pk0[1]; qv0.z = pk0[2]; qv0.w = pk0[3];
    uint4 qv1; qv1.x = pk1[0]; qv1.y = pk1[1]; qv1.z = pk1[2]; qv1.w = pk1[3];
    *(uint4*)&X[(2 * tokp) * 72 + grp * 8] = qv0;
    *(uint4*)&X[(2 * tokp + 1) * 72 + grp * 8] = qv1;
  }
  // ---- stage weights, float4-coalesced: thread -> (o = t>>2, c0 = (t&3)*16)
  {
    const int o = t >> 2, c0 = (t & 3) << 4;
    const float4* p4 = (const float4*)((side ? wk : wq) + o * 64 + c0);
    float4 f0 = p4[0], f1 = p4[1], f2 = p4[2], f3 = p4[3];
    uint4 qa, qb;
    qa.x = (u32)f2bf(f0.x) | ((u32)f2bf(f0.y) << 16);
    qa.y = (u32)f2bf(f0.z) | ((u32)f2bf(f0.w) << 16);
    qa.z = (u32)f2bf(f1.x) | ((u32)f2bf(f1.y) << 16);
    qa.w = (u32)f2bf(f1.z) | ((u32)f2bf(f1.w) << 16);
    qb.x = (u32)f2bf(f2.x) | ((u32)f2bf(f2.y) << 16);
    qb.y = (u32)f2bf(f2.z) | ((u32)f2bf(f2.w) << 16);
    qb.z = (u32)f2bf(f3.x) | ((u32)f2bf(f3.y) << 16);
    qb.w = (u32)f2bf(f3.z) | ((u32)f2bf(f3.w) << 16);
    *(uint4*)&W0[o * 72 + c0] = qa;
    *(uint4*)&W0[o * 72 + c0 + 8] = qb;
    if (side) {
      const float4* v4 = (const float4*)(wv + o * 64 + c0);
      float4 g0 = v4[0], g1 = v4[1], g2 = v4[2], g3 = v4[3];
      qa.x = (u32)f2bf(g0.x) | ((u32)f2bf(g0.y) << 16);
      qa.y = (u32)f2bf(g0.z) | ((u32)f2bf(g0.w) << 16);
      qa.z = (u32)f2bf(g1.x) | ((u32)f2bf(g1.y) << 16);
      qa.w = (u32)f2bf(g1.z) | ((u32)f2bf(g1.w) << 16);
      qb.x = (u32)f2bf(g2.x) | ((u32)f2bf(g2.y) << 16);
      qb.y = (u32)f2bf(g2.z) | ((u32)f2bf(g2.w) << 16);
      qb.z = (u32)f2bf(g3.x) | ((u32)f2bf(g3.y) << 16);
      qb.w = (u32)f2bf(g3.z) | ((u32)f2bf(g3.w) << 16);
      *(uint4*)&W1[o * 72 + c0] = qa;
      *(uint4*)&W1[o * 72 + c0 + 8] = qb;
    }
  }
  __syncthreads();

  const int lane = t & 63, w = t >> 6;
  const int l15 = lane & 15, qd = lane >> 4;
  const int tb = w * 16;                  // wave's 16 tokens

  bf16x8 af0 = *(const bf16x8*)&X[(tb + l15) * 72 + qd * 8];
  bf16x8 af1 = *(const bf16x8*)&X[(tb + l15) * 72 + 32 + qd * 8];

  // ---- Q (side 0) / K (side 1): A = X (rows tok), B = W0 (cols o) ----
  f32x4 acc[4];
#pragma unroll
  for (int nt = 0; nt < 4; ++nt) {
    bf16x8 b0 = *(const bf16x8*)&W0[(nt * 16 + l15) * 72 + qd * 8];
    bf16x8 b1 = *(const bf16x8*)&W0[(nt * 16 + l15) * 72 + 32 + qd * 8];
    f32x4 a = {0.f, 0.f, 0.f, 0.f};
    a = __builtin_amdgcn_mfma_f32_16x16x32_bf16(af0, b0, a, 0, 0, 0);
    a = __builtin_amdgcn_mfma_f32_16x16x32_bf16(af1, b1, a, 0, 0, 0);
    acc[nt] = a;
  }
  {
    const float* bias0 = side ? bk : bq;
    // Q scale = hid^-0.5 * log2(e); K unscaled
    const float sc = side ? 1.f : 0.18033688f;
    u16* dst0 = side ? Ko : Qo;
#pragma unroll
    for (int nt = 0; nt < 4; ++nt) {
      float bia = bias0[nt * 16 + l15];
#pragma unroll
      for (int e = 0; e < 4; ++e) {
        int tok = idx0 + tb + qd * 4 + e;     // D row = token
        dst0[(size_t)tok * 64 + nt * 16 + l15] = f2bf((acc[nt][e] + bia) * sc);
      }
    }
  }

  if (side) {
    // ---- V: A = Wv (rows c), B = X (cols tok) -> D = V^T directly ----
    f32x4 accv[4];
#pragma unroll
    for (int ct = 0; ct < 4; ++ct) {
      bf16x8 a0 = *(const bf16x8*)&W1[(ct * 16 + l15) * 72 + qd * 8];
      bf16x8 a1 = *(const bf16x8*)&W1[(ct * 16 + l15) * 72 + 32 + qd * 8];
      f32x4 a = {0.f, 0.f, 0.f, 0.f};
      a = __builtin_amdgcn_mfma_f32_16x16x32_bf16(a0, af0, a, 0, 0, 0);
      a = __builtin_amdgcn_mfma_f32_16x16x32_bf16(a1, af1, a, 0, 0, 0);
      accv[ct] = a;
    }
#pragma unroll
    for (int ct = 0; ct < 4; ++ct) {
#pragma unroll
      for (int e = 0; e < 4; ++e) {
        int c = ct * 16 + qd * 4 + e;          // D row = V channel
        float v = accv[ct][e] + bv[c];
        Vo[((size_t)(bb * 64 + c)) * 4096 + n0 + tb + l15] = f2bf(v);
      }
    }
  }
}

// ---------------------------------------------------------------------------
// Kernel 2: attention + fused output-conv/BN epilogue, barrier-free K-loop.
// grid (8 b, 64 qtile) x 256 threads = 4 independent waves.
// K-loop FROZEN at the verified r0/r7 optimum (64-q tile, (256,2), batched
// loads -> VGPR ~120, ~72.6us; see r0-r6 ledger in session notes).
// Epilogue change (r8): Y = BNaffine(Wo·Z) computed with Wo as the A operand
// (mirrors k_qkv's V^T pattern) -> D rows = o, cols = q, stored CHANNEL-OUTER
// Ya[b][64 o][4096 n]. Same 4x32B store coalescing; lets k_out read the
// bilinear corners as coalesced u32 runs instead of 16x uint4 gather.
// BN affine (A,B per o) precomputed into LDS at kernel start.
// ---------------------------------------------------------------------------
__global__ __launch_bounds__(256, 2) void k_attn(
    const u16* __restrict__ Qg, const u16* __restrict__ Kg,
    const u16* __restrict__ Vg,
    const float* __restrict__ wo, const float* __restrict__ bo,
    const float* __restrict__ gam, const float* __restrict__ bet,
    const float* __restrict__ mean, const float* __restrict__ var,
    u16* __restrict__ Ya)
{
  __shared__ __align__(16) u16 Pb[4 * 4608];   // per-wave [64 q][72] P / partial-Z
  __shared__ __align__(16) u16 Wl[4608];       // Wo [64 o][72]
  __shared__ __align__(16) u16 Zc[4608];       // combined Z [64 q][72]
  __shared__ float lb[256];                    // [wave][64 q] denominators
  __shared__ float Afs[64], Bfs[64];           // BN affine per o

  const int b  = blockIdx.x;                   // batch -> XCD affinity
  const int q0 = blockIdx.y * 64;
  const int t  = threadIdx.x;
  const int lane = t & 63, w = t >> 6;
  const int l15 = lane & 15, qd = lane >> 4;
  u16* P = Pb + w * 4608;

  // ---- stage Wo (bf16, rounded) + BN affine coefficients ----
  {
    const int o = t >> 2, c0 = (t & 3) << 4;
    const float4* p4 = (const float4*)(wo + o * 64 + c0);
    float4 f0 = p4[0], f1 = p4[1], f2 = p4[2], f3 = p4[3];
    uint4 qa, qb;
    qa.x = (u32)f2bf(f0.x) | ((u32)f2bf(f0.y) << 16);
    qa.y = (u32)f2bf(f0.z) | ((u32)f2bf(f0.w) << 16);
    qa.z = (u32)f2bf(f1.x) | ((u32)f2bf(f1.y) << 16);
    qa.w = (u32)f2bf(f1.z) | ((u32)f2bf(f1.w) << 16);
    qb.x = (u32)f2bf(f2.x) | ((u32)f2bf(f2.y) << 16);
    qb.y = (u32)f2bf(f2.z) | ((u32)f2bf(f2.w) << 16);
    qb.z = (u32)f2bf(f3.x) | ((u32)f2bf(f3.y) << 16);
    qb.w = (u32)f2bf(f3.z) | ((u32)f2bf(f3.w) << 16);
    *(uint4*)&Wl[o * 72 + c0] = qa;
    *(uint4*)&Wl[o * 72 + c0 + 8] = qb;
    if (t < 64) {
      float A = gam[t] * __frsqrt_rn(var[t] + 1e-5f);
      Afs[t] = A;
      Bfs[t] = (bo[t] - mean[t]) * A + bet[t];
    }
  }

  // ---- Q fragments (B-operand, scale*log2e pre-folded) ----
  bf16x8 qf[4][2];
#pragma unroll
  for (int qt = 0; qt < 4; ++qt) {
    const u16* p = Qg + ((size_t)(b * 4096 + q0 + qt * 16 + l15)) * 64 + qd * 8;
    qf[qt][0] = *(const bf16x8*)p;
    qf[qt][1] = *(const bf16x8*)(p + 32);
  }

  f32x4 zacc[4][4];                            // [ct][qt]
#pragma unroll
  for (int i = 0; i < 4; ++i)
#pragma unroll
    for (int j = 0; j < 4; ++j) {
      f32x4 z = {0.f, 0.f, 0.f, 0.f};
      zacc[i][j] = z;
    }
  float lacc[4] = {0.f, 0.f, 0.f, 0.f};

  for (int tile = 0; tile < 16; ++tile) {
    const int n0 = w * 1024 + tile * 64;

    // batch all K+V loads at tile top; other resident wave's softmax hides them
    bf16x8 kf[4][2], vf[4][2];
#pragma unroll
    for (int mt = 0; mt < 4; ++mt) {
      const u16* p = Kg + ((size_t)(b * 4096 + n0 + mt * 16 + l15)) * 64 + qd * 8;
      kf[mt][0] = *(const bf16x8*)p;
      kf[mt][1] = *(const bf16x8*)(p + 32);
    }
#pragma unroll
    for (int ct = 0; ct < 4; ++ct) {
      const u16* p = Vg + ((size_t)(b * 64 + ct * 16 + l15)) * 4096 + n0 + qd * 8;
      vf[ct][0] = *(const bf16x8*)p;
      vf[ct][1] = *(const bf16x8*)(p + 32);
    }

    // ---- S^T = K·Q^T, exp2, pack P[q][key] (perm-truncated bf16) ----
#pragma unroll
    for (int qt = 0; qt < 4; ++qt) {
#pragma unroll
      for (int mt = 0; mt < 4; ++mt) {
        f32x4 a = {0.f, 0.f, 0.f, 0.f};
        __builtin_amdgcn_s_setprio(1);
        a = __builtin_amdgcn_mfma_f32_16x16x32_bf16(kf[mt][0], qf[qt][0], a, 0, 0, 0);
        a = __builtin_amdgcn_mfma_f32_16x16x32_bf16(kf[mt][1], qf[qt][1], a, 0, 0, 0);
        __builtin_amdgcn_s_setprio(0);
        float p0 = __builtin_amdgcn_exp2f(a[0]);
        float p1 = __builtin_amdgcn_exp2f(a[1]);
        float p2 = __builtin_amdgcn_exp2f(a[2]);
        float p3 = __builtin_amdgcn_exp2f(a[3]);
        lacc[qt] += (p0 + p1) + (p2 + p3);
        uint2 pw;
        pw.x = packhi(p0, p1);
        pw.y = packhi(p2, p3);
        *(uint2*)&P[(qt * 16 + l15) * 72 + mt * 16 + qd * 4] = pw;
      }
    }
    // ---- Z^T += V^T · P^T ----
#pragma unroll
    for (int qt = 0; qt < 4; ++qt) {
      bf16x8 pf0 = *(const bf16x8*)&P[(qt * 16 + l15) * 72 + qd * 8];
      bf16x8 pf1 = *(const bf16x8*)&P[(qt * 16 + l15) * 72 + 32 + qd * 8];
      __builtin_amdgcn_s_setprio(1);
#pragma unroll
      for (int ct = 0; ct < 4; ++ct) {
        zacc[ct][qt] = __builtin_amdgcn_mfma_f32_16x16x32_bf16(vf[ct][0], pf0, zacc[ct][qt], 0, 0, 0);
        zacc[ct][qt] = __builtin_amdgcn_mfma_f32_16x16x32_bf16(vf[ct][1], pf1, zacc[ct][qt], 0, 0, 0);
      }
      __builtin_amdgcn_s_setprio(0);
    }
  }

  // ---- epilogue: denominators + unnormalized partial Z ([q][c] bf16) ----
#pragma unroll
  for (int qt = 0; qt < 4; ++qt) {
    float l = lacc[qt];
    l += __shfl_xor(l, 16);
    l += __shfl_xor(l, 32);
    lb[w * 64 + qt * 16 + l15] = l;   // all quads write same value: benign
  }
#pragma unroll
  for (int qt = 0; qt < 4; ++qt)
#pragma unroll
    for (int ct = 0; ct < 4; ++ct) {
      uint2 pw;
      pw.x = packhi(zacc[ct][qt][0], zacc[ct][qt][1]);
      pw.y = packhi(zacc[ct][qt][2], zacc[ct][qt][3]);
      *(uint2*)&P[(qt * 16 + l15) * 72 + ct * 16 + qd * 4] = pw;
    }
  __syncthreads();

  // ---- combine 4 key-splits + normalize -> Zc[q][72] bf16 ----
  {
    const u32* Pu = (const u32*)Pb;            // wave stride 2304 u32, row 36
    u32* Zu = (u32*)Zc;
#pragma unroll
    for (int i = 0; i < 8; ++i) {
      int cell = i * 256 + t;                  // 0..2047
      int q = cell >> 5, cu = cell & 31;
      float s0 = 0.f, s1 = 0.f;
#pragma unroll
      for (int ww = 0; ww < 4; ++ww) {
        u32 v = Pu[ww * 2304 + q * 36 + cu];
        s0 += bflo(v);
        s1 += bfhi(v);
      }
      float inv = 1.f / (lb[q] + lb[64 + q] + lb[128 + q] + lb[192 + q]);
      Zu[q * 36 + cu] = packhi(s0 * inv, s1 * inv);
    }
  }
  __syncthreads();

  // ---- Y^T = affine(Wo · Z): A = Wl (rows o), B = Zc (rows q) ----
  // D row (qd*4+e) = o, D col (l15) = q -> store channel-outer Ya[b][o][n].
  {
    bf16x8 af0 = *(const bf16x8*)&Zc[(w * 16 + l15) * 72 + qd * 8];
    bf16x8 af1 = *(const bf16x8*)&Zc[(w * 16 + l15) * 72 + 32 + qd * 8];
#pragma unroll
    for (int nt = 0; nt < 4; ++nt) {
      bf16x8 b0 = *(const bf16x8*)&Wl[(nt * 16 + l15) * 72 + qd * 8];
      bf16x8 b1 = *(const bf16x8*)&Wl[(nt * 16 + l15) * 72 + 32 + qd * 8];
      f32x4 y = {0.f, 0.f, 0.f, 0.f};
      y = __builtin_amdgcn_mfma_f32_16x16x32_bf16(b0, af0, y, 0, 0, 0);
      y = __builtin_amdgcn_mfma_f32_16x16x32_bf16(b1, af1, y, 0, 0, 0);
#pragma unroll
      for (int e = 0; e < 4; ++e) {
        const int o = nt * 16 + qd * 4 + e;
        float v = y[e] * Afs[o] + Bfs[o];
        Ya[((size_t)(b * 64 + o)) * 4096 + q0 + w * 16 + l15] =
            (u16)(__float_as_uint(v) >> 16);
      }
    }
  }
}

// ---------------------------------------------------------------------------
// Kernel 3: bilinear 2x upsample of channel-outer Ya + LeakyReLU + residual.
// grid 8192 x 256: thread = (b, o, i, j-quad of 4 consecutive j).
// rgb read + out write are one float4 each (wave: 1KB contiguous).
// Ya[b][o][y*64+x] corners: x range for j=4g..4g+3 is [2g-1, 2g+2] -> 3
// consecutive u32 words per row, 2 rows = 6 coalesced u32 loads (128B runs).
// No LDS, ~30 VGPR -> 8 waves/SIMD for latency hiding.
// ---------------------------------------------------------------------------
__global__ __launch_bounds__(256, 8) void k_out(
    const u16* __restrict__ Ya, const float* __restrict__ rgb,
    float* __restrict__ out)
{
  const int tid = blockIdx.x * 256 + threadIdx.x;  // 0..2097151
  const int g = tid & 31;                          // j-quad (j = 4g..4g+3)
  const int i = (tid >> 5) & 127;
  const int o = (tid >> 12) & 63;
  const int b = tid >> 18;

  float ys = fmaxf(0.5f * (float)i - 0.25f, 0.f);
  int   y0 = (int)ys;
  float wy = ys - (float)y0;
  int   y1 = min(y0 + 1, 63);

  const u32* Yw = (const u32*)(Ya + ((size_t)(b * 64 + o)) * 4096);
  const int base0 = y0 * 32, base1 = y1 * 32;
  const int gm = (g == 0) ? 0 : g - 1;
  const int gp = (g == 31) ? 31 : g + 1;

  u32 tm = Yw[base0 + gm], t0 = Yw[base0 + g], tp = Yw[base0 + gp];
  u32 bm = Yw[base1 + gm], b0w = Yw[base1 + g], bp = Yw[base1 + gp];

  const float iw = 1.f - wy;
  // row-interpolated values at x = 2g-1, 2g, 2g+1, 2g+2
  float r_m1 = iw * bfhi(tm) + wy * bfhi(bm);
  float r_0  = iw * bflo(t0) + wy * bflo(b0w);
  float r_1  = iw * bfhi(t0) + wy * bfhi(b0w);
  float r_2  = iw * bflo(tp) + wy * bflo(bp);

  // j=4g:   x0=2g-1, wx=.75 (g=0: x0=0, wx=0)
  // j=4g+1: x0=2g,   wx=.25
  // j=4g+2: x0=2g,   wx=.75
  // j=4g+3: x0=2g+1, wx=.25 (g=31: x1 clamped -> ry(63))
  float v0 = (g == 0)  ? r_0 : 0.25f * r_m1 + 0.75f * r_0;
  float v1 = 0.75f * r_0 + 0.25f * r_1;
  float v2 = 0.25f * r_0 + 0.75f * r_1;
  float v3 = (g == 31) ? r_1 : 0.75f * r_1 + 0.25f * r_2;

  v0 = (v0 >= 0.f) ? v0 : 0.2f * v0;
  v1 = (v1 >= 0.f) ? v1 : 0.2f * v1;
  v2 = (v2 >= 0.f) ? v2 : 0.2f * v2;
  v3 = (v3 >= 0.f) ? v3 : 0.2f * v3;

  const size_t pix = ((size_t)((b * 64 + o) * 128 + i)) * 128 + g * 4;
  float4 rv = *(const float4*)(rgb + pix);
  float4 ov;
  ov.x = rv.x + v0;
  ov.y = rv.y + v1;
  ov.z = rv.z + v2;
  ov.w = rv.w + v3;
  *(float4*)(out + pix) = ov;
}

// ---------------------------------------------------------------------------
extern "C" void kernel_launch(void* const* d_in, const int* in_sizes, int n_in,
                              void* d_out, int out_size, void* d_ws, size_t ws_size,
                              hipStream_t stream) {
  (void)in_sizes; (void)n_in; (void)out_size; (void)ws_size;
  const float* rgb  = (const float*)d_in[0];
  const float* freq = (const float*)d_in[1];
  const float* wq   = (const float*)d_in[2];
  const float* bq   = (const float*)d_in[3];
  const float* wk   = (const float*)d_in[4];
  const float* bk   = (const float*)d_in[5];
  const float* wv   = (const float*)d_in[6];
  const float* bv   = (const float*)d_in[7];
  const float* wo   = (const float*)d_in[8];
  const float* bo   = (const float*)d_in[9];
  const float* gam  = (const float*)d_in[10];
  const float* bet  = (const float*)d_in[11];
  const float* mean = (const float*)d_in[12];
  const float* var  = (const float*)d_in[13];

  char* ws = (char*)d_ws;
  u16* Qw = (u16*)(ws);               // 8*4096*64 bf16 = 4 MiB
  u16* Kw = (u16*)(ws + 4194304);     // 4 MiB
  u16* Vw = (u16*)(ws + 8388608);     // 4 MiB (transposed [b][c][n])
  u16* Yw = (u16*)(ws + 12582912);    // 4 MiB  Ya[b][64 o][4096 n] (ch-outer)

  k_qkv<<<dim3(1024), dim3(256), 0, stream>>>(rgb, freq, wq, bq, wk, bk, wv, bv,
                                              Qw, Kw, Vw);
  k_attn<<<dim3(8, 64), dim3(256), 0, stream>>>(Qw, Kw, Vw, wo, bo, gam, bet,
                                                mean, var, Yw);
  k_out<<<dim3(8192), dim3(256), 0, stream>>>(Yw, rgb, (float*)d_out);
}

// Round 9
// 200.871 us; speedup vs baseline: 1.4315x; 1.0022x over previous
//
#include <hip/hip_runtime.h>
#include <hip/hip_bf16.h>

typedef unsigned short u16;
typedef unsigned int   u32;
typedef __attribute__((ext_vector_type(8))) short bf16x8;
typedef __attribute__((ext_vector_type(4))) float f32x4;

__device__ __forceinline__ u16 f2bf(float f) {
  u32 u = __float_as_uint(f);
  u32 r = u + 0x7fffu + ((u >> 16) & 1u);
  return (u16)(r >> 16);
}
__device__ __forceinline__ float bflo(u32 u) { return __uint_as_float(u << 16); }
__device__ __forceinline__ float bfhi(u32 u) { return __uint_as_float(u & 0xffff0000u); }
// pack (hi16(b)<<16)|hi16(a) in one v_perm (truncation-to-bf16; bias cancels
// in softmax normalization, ~0.4% rel elsewhere — noise vs 0.109 threshold)
__device__ __forceinline__ u32 packhi(float a, float b) {
  return __builtin_amdgcn_perm(__float_as_uint(b), __float_as_uint(a), 0x07060302u);
}

// ---------------------------------------------------------------------------
// Kernel 1: avgpool 2x2 + Q/K/V 1x1-conv projections via MFMA.
// grid 1024 x 256 (4 waves). side = blockIdx&1 (0: rgb->Q, 1: freq->K,V).
// Q,K stored [b][n][64] bf16; V stored [b][64][n] bf16.
// Q pre-scaled by hid^-0.5 * log2(e) so k_attn can use exp2 directly.
// r9: MFMA outputs are staged through the (dead) LDS buffers and written as
// 2x uint4 per thread (128B-contiguous runs) instead of 16 scalar u16 stores
// per thread per tensor — 8x fewer store instructions, fully coalesced.
// ---------------------------------------------------------------------------
__global__ __launch_bounds__(256, 4) void k_qkv(
    const float* __restrict__ rgb, const float* __restrict__ freq,
    const float* __restrict__ wq, const float* __restrict__ bq,
    const float* __restrict__ wk, const float* __restrict__ bk,
    const float* __restrict__ wv, const float* __restrict__ bv,
    u16* __restrict__ Qo, u16* __restrict__ Ko, u16* __restrict__ Vo)
{
  __shared__ __align__(16) u16 sm[3 * 4608];
  u16* X  = sm;             // [64][72] pooled input tokens -> Q/K staging
  u16* W0 = sm + 4608;      // [64][72] wq or wk            -> V staging
  u16* W1 = sm + 9216;      // [64][72] wv (side 1 only)

  const int t    = threadIdx.x;
  const int side = blockIdx.x & 1;
  const int seg  = blockIdx.x >> 1;       // 0..511
  const int idx0 = seg * 64;              // global token base (b*4096+n)
  const int bb   = idx0 >> 12;
  const int n0   = idx0 & 4095;
  const int h    = n0 >> 6;               // pooled row (uniform per block)
  const float* src = side ? freq : rgb;

  // ---- stage pooled X: thread = (token-pair, channel-granule), float4 ----
  const size_t sbase = (size_t)bb * 64 * 16384 + (size_t)(2 * h) * 128;
  {
    const int tokp = t & 31;              // token pair 0..31 (lane-consecutive)
    const int grp  = t >> 5;              // channel granule 0..7
    const float* p0 = src + sbase + 4 * tokp + (size_t)(grp * 8) * 16384;
    u32 pk0[4], pk1[4];
#pragma unroll
    for (int c = 0; c < 8; c += 2) {
      const float* pa = p0 + (size_t)c * 16384;
      float4 a0 = *(const float4*)pa;
      float4 a1 = *(const float4*)(pa + 128);
      float t0a = 0.25f * ((a0.x + a0.y) + (a1.x + a1.y));
      float t1a = 0.25f * ((a0.z + a0.w) + (a1.z + a1.w));
      const float* pb = pa + 16384;
      float4 c0 = *(const float4*)pb;
      float4 c1 = *(const float4*)(pb + 128);
      float t0b = 0.25f * ((c0.x + c0.y) + (c1.x + c1.y));
      float t1b = 0.25f * ((c0.z + c0.w) + (c1.z + c1.w));
      pk0[c >> 1] = (u32)f2bf(t0a) | ((u32)f2bf(t0b) << 16);
      pk1[c >> 1] = (u32)f2bf(t1a) | ((u32)f2bf(t1b) << 16);
    }
    uint4 qv0; qv0.x = pk0[0]; qv0.y = pk0[1]; qv0.z = pk0[2]; qv0.w = pk0[3];
    uint4 qv1; qv1.x = pk1[0]; qv1.y = pk1[1]; qv1.z = pk1[2]; qv1.w = pk1[3];
    *(uint4*)&X[(2 * tokp) * 72 + grp * 8] = qv0;
    *(uint4*)&X[(2 * tokp + 1) * 72 + grp * 8] = qv1;
  }
  // ---- stage weights, float4-coalesced: thread -> (o = t>>2, c0 = (t&3)*16)
  {
    const int o = t >> 2, c0 = (t & 3) << 4;
    const float4* p4 = (const float4*)((side ? wk : wq) + o * 64 + c0);
    float4 f0 = p4[0], f1 = p4[1], f2 = p4[2], f3 = p4[3];
    uint4 qa, qb;
    qa.x = (u32)f2bf(f0.x) | ((u32)f2bf(f0.y) << 16);
    qa.y = (u32)f2bf(f0.z) | ((u32)f2bf(f0.w) << 16);
    qa.z = (u32)f2bf(f1.x) | ((u32)f2bf(f1.y) << 16);
    qa.w = (u32)f2bf(f1.z) | ((u32)f2bf(f1.w) << 16);
    qb.x = (u32)f2bf(f2.x) | ((u32)f2bf(f2.y) << 16);
    qb.y = (u32)f2bf(f2.z) | ((u32)f2bf(f2.w) << 16);
    qb.z = (u32)f2bf(f3.x) | ((u32)f2bf(f3.y) << 16);
    qb.w = (u32)f2bf(f3.z) | ((u32)f2bf(f3.w) << 16);
    *(uint4*)&W0[o * 72 + c0] = qa;
    *(uint4*)&W0[o * 72 + c0 + 8] = qb;
    if (side) {
      const float4* v4 = (const float4*)(wv + o * 64 + c0);
      float4 g0 = v4[0], g1 = v4[1], g2 = v4[2], g3 = v4[3];
      qa.x = (u32)f2bf(g0.x) | ((u32)f2bf(g0.y) << 16);
      qa.y = (u32)f2bf(g0.z) | ((u32)f2bf(g0.w) << 16);
      qa.z = (u32)f2bf(g1.x) | ((u32)f2bf(g1.y) << 16);
      qa.w = (u32)f2bf(g1.z) | ((u32)f2bf(g1.w) << 16);
      qb.x = (u32)f2bf(g2.x) | ((u32)f2bf(g2.y) << 16);
      qb.y = (u32)f2bf(g2.z) | ((u32)f2bf(g2.w) << 16);
      qb.z = (u32)f2bf(g3.x) | ((u32)f2bf(g3.y) << 16);
      qb.w = (u32)f2bf(g3.z) | ((u32)f2bf(g3.w) << 16);
      *(uint4*)&W1[o * 72 + c0] = qa;
      *(uint4*)&W1[o * 72 + c0 + 8] = qb;
    }
  }
  __syncthreads();

  const int lane = t & 63, w = t >> 6;
  const int l15 = lane & 15, qd = lane >> 4;
  const int tb = w * 16;                  // wave's 16 tokens

  bf16x8 af0 = *(const bf16x8*)&X[(tb + l15) * 72 + qd * 8];
  bf16x8 af1 = *(const bf16x8*)&X[(tb + l15) * 72 + 32 + qd * 8];

  // ---- Q (side 0) / K (side 1): A = X (rows tok), B = W0 (cols o) ----
  f32x4 acc[4];
#pragma unroll
  for (int nt = 0; nt < 4; ++nt) {
    bf16x8 b0 = *(const bf16x8*)&W0[(nt * 16 + l15) * 72 + qd * 8];
    bf16x8 b1 = *(const bf16x8*)&W0[(nt * 16 + l15) * 72 + 32 + qd * 8];
    f32x4 a = {0.f, 0.f, 0.f, 0.f};
    a = __builtin_amdgcn_mfma_f32_16x16x32_bf16(af0, b0, a, 0, 0, 0);
    a = __builtin_amdgcn_mfma_f32_16x16x32_bf16(af1, b1, a, 0, 0, 0);
    acc[nt] = a;
  }
  // ---- V (side 1): A = Wv (rows c), B = X (cols tok) -> D = V^T ----
  f32x4 accv[4];
  if (side) {
#pragma unroll
    for (int ct = 0; ct < 4; ++ct) {
      bf16x8 a0 = *(const bf16x8*)&W1[(ct * 16 + l15) * 72 + qd * 8];
      bf16x8 a1 = *(const bf16x8*)&W1[(ct * 16 + l15) * 72 + 32 + qd * 8];
      f32x4 a = {0.f, 0.f, 0.f, 0.f};
      a = __builtin_amdgcn_mfma_f32_16x16x32_bf16(a0, af0, a, 0, 0, 0);
      a = __builtin_amdgcn_mfma_f32_16x16x32_bf16(a1, af1, a, 0, 0, 0);
      accv[ct] = a;
    }
  }

  // ---- stage results to LDS (X/W0 now dead), then coalesced stores ----
  __syncthreads();                        // all waves done reading X/W0/W1
  {
    const float* bias0 = side ? bk : bq;
    const float sc = side ? 1.f : 0.18033688f;   // Q: hid^-0.5 * log2(e)
#pragma unroll
    for (int nt = 0; nt < 4; ++nt) {
      float bia = bias0[nt * 16 + l15];
#pragma unroll
      for (int e = 0; e < 4; ++e)
        X[(tb + qd * 4 + e) * 72 + nt * 16 + l15] = f2bf((acc[nt][e] + bia) * sc);
    }
    if (side) {
#pragma unroll
      for (int ct = 0; ct < 4; ++ct)
#pragma unroll
        for (int e = 0; e < 4; ++e) {
          int c = ct * 16 + qd * 4 + e;          // D row = V channel
          W0[c * 72 + tb + l15] = f2bf(accv[ct][e] + bv[c]);
        }
    }
  }
  __syncthreads();
  {
    const int r = t >> 2, c4 = (t & 3) << 4;     // r = token (Q/K) or channel (V)
    u16* dst0 = side ? Ko : Qo;
    uint4 a0 = *(const uint4*)&X[r * 72 + c4];
    uint4 a1 = *(const uint4*)&X[r * 72 + c4 + 8];
    u16* d = dst0 + (size_t)(idx0 + r) * 64;
    *(uint4*)&d[c4] = a0;
    *(uint4*)&d[c4 + 8] = a1;
    if (side) {
      uint4 v0 = *(const uint4*)&W0[r * 72 + c4];
      uint4 v1 = *(const uint4*)&W0[r * 72 + c4 + 8];
      u16* dv = Vo + ((size_t)(bb * 64 + r)) * 4096 + n0;
      *(uint4*)&dv[c4] = v0;
      *(uint4*)&dv[c4 + 8] = v1;
    }
  }
}

// ---------------------------------------------------------------------------
// Kernel 2: attention + fused output-conv/BN epilogue, barrier-free K-loop.
// grid (8 b, 64 qtile) x 256 threads = 4 independent waves.
// K-loop FROZEN at the verified r0/r7 optimum (64-q tile, (256,2), batched
// loads -> VGPR ~120, ~72.6us; see r0-r6 ledger in session notes).
// Epilogue: Y^T = BNaffine(Wo·Z) channel-outer (Ya[b][64 o][4096 n]) for
// k_out's coalesced reads. r9: Y staged through Pb (dead after combine) and
// stored as 2x uint4/thread (128B runs) instead of 16 scalar u16 stores —
// recovers the r8 epilogue regression (77 vs 72.6us).
// ---------------------------------------------------------------------------
__global__ __launch_bounds__(256, 2) void k_attn(
    const u16* __restrict__ Qg, const u16* __restrict__ Kg,
    const u16* __restrict__ Vg,
    const float* __restrict__ wo, const float* __restrict__ bo,
    const float* __restrict__ gam, const float* __restrict__ bet,
    const float* __restrict__ mean, const float* __restrict__ var,
    u16* __restrict__ Ya)
{
  __shared__ __align__(16) u16 Pb[4 * 4608];   // per-wave [64 q][72] P / partial-Z / Y staging
  __shared__ __align__(16) u16 Wl[4608];       // Wo [64 o][72]
  __shared__ __align__(16) u16 Zc[4608];       // combined Z [64 q][72]
  __shared__ float lb[256];                    // [wave][64 q] denominators
  __shared__ float Afs[64], Bfs[64];           // BN affine per o

  const int b  = blockIdx.x;                   // batch -> XCD affinity
  const int q0 = blockIdx.y * 64;
  const int t  = threadIdx.x;
  const int lane = t & 63, w = t >> 6;
  const int l15 = lane & 15, qd = lane >> 4;
  u16* P = Pb + w * 4608;

  // ---- stage Wo (bf16, rounded) + BN affine coefficients ----
  {
    const int o = t >> 2, c0 = (t & 3) << 4;
    const float4* p4 = (const float4*)(wo + o * 64 + c0);
    float4 f0 = p4[0], f1 = p4[1], f2 = p4[2], f3 = p4[3];
    uint4 qa, qb;
    qa.x = (u32)f2bf(f0.x) | ((u32)f2bf(f0.y) << 16);
    qa.y = (u32)f2bf(f0.z) | ((u32)f2bf(f0.w) << 16);
    qa.z = (u32)f2bf(f1.x) | ((u32)f2bf(f1.y) << 16);
    qa.w = (u32)f2bf(f1.z) | ((u32)f2bf(f1.w) << 16);
    qb.x = (u32)f2bf(f2.x) | ((u32)f2bf(f2.y) << 16);
    qb.y = (u32)f2bf(f2.z) | ((u32)f2bf(f2.w) << 16);
    qb.z = (u32)f2bf(f3.x) | ((u32)f2bf(f3.y) << 16);
    qb.w = (u32)f2bf(f3.z) | ((u32)f2bf(f3.w) << 16);
    *(uint4*)&Wl[o * 72 + c0] = qa;
    *(uint4*)&Wl[o * 72 + c0 + 8] = qb;
    if (t < 64) {
      float A = gam[t] * __frsqrt_rn(var[t] + 1e-5f);
      Afs[t] = A;
      Bfs[t] = (bo[t] - mean[t]) * A + bet[t];
    }
  }

  // ---- Q fragments (B-operand, scale*log2e pre-folded) ----
  bf16x8 qf[4][2];
#pragma unroll
  for (int qt = 0; qt < 4; ++qt) {
    const u16* p = Qg + ((size_t)(b * 4096 + q0 + qt * 16 + l15)) * 64 + qd * 8;
    qf[qt][0] = *(const bf16x8*)p;
    qf[qt][1] = *(const bf16x8*)(p + 32);
  }

  f32x4 zacc[4][4];                            // [ct][qt]
#pragma unroll
  for (int i = 0; i < 4; ++i)
#pragma unroll
    for (int j = 0; j < 4; ++j) {
      f32x4 z = {0.f, 0.f, 0.f, 0.f};
      zacc[i][j] = z;
    }
  float lacc[4] = {0.f, 0.f, 0.f, 0.f};

  for (int tile = 0; tile < 16; ++tile) {
    const int n0 = w * 1024 + tile * 64;

    // batch all K+V loads at tile top; other resident wave's softmax hides them
    bf16x8 kf[4][2], vf[4][2];
#pragma unroll
    for (int mt = 0; mt < 4; ++mt) {
      const u16* p = Kg + ((size_t)(b * 4096 + n0 + mt * 16 + l15)) * 64 + qd * 8;
      kf[mt][0] = *(const bf16x8*)p;
      kf[mt][1] = *(const bf16x8*)(p + 32);
    }
#pragma unroll
    for (int ct = 0; ct < 4; ++ct) {
      const u16* p = Vg + ((size_t)(b * 64 + ct * 16 + l15)) * 4096 + n0 + qd * 8;
      vf[ct][0] = *(const bf16x8*)p;
      vf[ct][1] = *(const bf16x8*)(p + 32);
    }

    // ---- S^T = K·Q^T, exp2, pack P[q][key] (perm-truncated bf16) ----
#pragma unroll
    for (int qt = 0; qt < 4; ++qt) {
#pragma unroll
      for (int mt = 0; mt < 4; ++mt) {
        f32x4 a = {0.f, 0.f, 0.f, 0.f};
        __builtin_amdgcn_s_setprio(1);
        a = __builtin_amdgcn_mfma_f32_16x16x32_bf16(kf[mt][0], qf[qt][0], a, 0, 0, 0);
        a = __builtin_amdgcn_mfma_f32_16x16x32_bf16(kf[mt][1], qf[qt][1], a, 0, 0, 0);
        __builtin_amdgcn_s_setprio(0);
        float p0 = __builtin_amdgcn_exp2f(a[0]);
        float p1 = __builtin_amdgcn_exp2f(a[1]);
        float p2 = __builtin_amdgcn_exp2f(a[2]);
        float p3 = __builtin_amdgcn_exp2f(a[3]);
        lacc[qt] += (p0 + p1) + (p2 + p3);
        uint2 pw;
        pw.x = packhi(p0, p1);
        pw.y = packhi(p2, p3);
        *(uint2*)&P[(qt * 16 + l15) * 72 + mt * 16 + qd * 4] = pw;
      }
    }
    // ---- Z^T += V^T · P^T ----
#pragma unroll
    for (int qt = 0; qt < 4; ++qt) {
      bf16x8 pf0 = *(const bf16x8*)&P[(qt * 16 + l15) * 72 + qd * 8];
      bf16x8 pf1 = *(const bf16x8*)&P[(qt * 16 + l15) * 72 + 32 + qd * 8];
      __builtin_amdgcn_s_setprio(1);
#pragma unroll
      for (int ct = 0; ct < 4; ++ct) {
        zacc[ct][qt] = __builtin_amdgcn_mfma_f32_16x16x32_bf16(vf[ct][0], pf0, zacc[ct][qt], 0, 0, 0);
        zacc[ct][qt] = __builtin_amdgcn_mfma_f32_16x16x32_bf16(vf[ct][1], pf1, zacc[ct][qt], 0, 0, 0);
      }
      __builtin_amdgcn_s_setprio(0);
    }
  }

  // ---- epilogue: denominators + unnormalized partial Z ([q][c] bf16) ----
#pragma unroll
  for (int qt = 0; qt < 4; ++qt) {
    float l = lacc[qt];
    l += __shfl_xor(l, 16);
    l += __shfl_xor(l, 32);
    lb[w * 64 + qt * 16 + l15] = l;   // all quads write same value: benign
  }
#pragma unroll
  for (int qt = 0; qt < 4; ++qt)
#pragma unroll
    for (int ct = 0; ct < 4; ++ct) {
      uint2 pw;
      pw.x = packhi(zacc[ct][qt][0], zacc[ct][qt][1]);
      pw.y = packhi(zacc[ct][qt][2], zacc[ct][qt][3]);
      *(uint2*)&P[(qt * 16 + l15) * 72 + ct * 16 + qd * 4] = pw;
    }
  __syncthreads();

  // ---- combine 4 key-splits + normalize -> Zc[q][72] bf16 ----
  {
    const u32* Pu = (const u32*)Pb;            // wave stride 2304 u32, row 36
    u32* Zu = (u32*)Zc;
#pragma unroll
    for (int i = 0; i < 8; ++i) {
      int cell = i * 256 + t;                  // 0..2047
      int q = cell >> 5, cu = cell & 31;
      float s0 = 0.f, s1 = 0.f;
#pragma unroll
      for (int ww = 0; ww < 4; ++ww) {
        u32 v = Pu[ww * 2304 + q * 36 + cu];
        s0 += bflo(v);
        s1 += bfhi(v);
      }
      float inv = 1.f / (lb[q] + lb[64 + q] + lb[128 + q] + lb[192 + q]);
      Zu[q * 36 + cu] = packhi(s0 * inv, s1 * inv);
    }
  }
  __syncthreads();

  // ---- Y^T = affine(Wo · Z): A = Wl (rows o), B = Zc (rows q) ----
  // D row (qd*4+e) = o, D col (l15) = q. Stage into Pb (dead), then
  // 2x uint4/thread coalesced store to channel-outer Ya[b][o][n].
  {
    u16* Ys = Pb;                              // [64 o][72 q] staging
    bf16x8 af0 = *(const bf16x8*)&Zc[(w * 16 + l15) * 72 + qd * 8];
    bf16x8 af1 = *(const bf16x8*)&Zc[(w * 16 + l15) * 72 + 32 + qd * 8];
#pragma unroll
    for (int nt = 0; nt < 4; ++nt) {
      bf16x8 b0 = *(const bf16x8*)&Wl[(nt * 16 + l15) * 72 + qd * 8];
      bf16x8 b1 = *(const bf16x8*)&Wl[(nt * 16 + l15) * 72 + 32 + qd * 8];
      f32x4 y = {0.f, 0.f, 0.f, 0.f};
      y = __builtin_amdgcn_mfma_f32_16x16x32_bf16(b0, af0, y, 0, 0, 0);
      y = __builtin_amdgcn_mfma_f32_16x16x32_bf16(b1, af1, y, 0, 0, 0);
#pragma unroll
      for (int e = 0; e < 4; ++e) {
        const int o = nt * 16 + qd * 4 + e;
        float v = y[e] * Afs[o] + Bfs[o];
        Ys[o * 72 + w * 16 + l15] = (u16)(__float_as_uint(v) >> 16);
      }
    }
  }
  __syncthreads();
  {
    const int o = t >> 2, c4 = (t & 3) << 4;
    uint4 y0 = *(const uint4*)&Pb[o * 72 + c4];
    uint4 y1 = *(const uint4*)&Pb[o * 72 + c4 + 8];
    u16* d = Ya + ((size_t)(b * 64 + o)) * 4096 + q0;
    *(uint4*)&d[c4] = y0;
    *(uint4*)&d[c4 + 8] = y1;
  }
}

// ---------------------------------------------------------------------------
// Kernel 3: bilinear 2x upsample of channel-outer Ya + LeakyReLU + residual.
// grid 8192 x 256: thread = (b, o, i, j-quad of 4 consecutive j).
// rgb read + out write are one float4 each (wave: 1KB contiguous).
// Ya corners: 6 coalesced u32 loads. No LDS, 8 waves/SIMD.
// ---------------------------------------------------------------------------
__global__ __launch_bounds__(256, 8) void k_out(
    const u16* __restrict__ Ya, const float* __restrict__ rgb,
    float* __restrict__ out)
{
  const int tid = blockIdx.x * 256 + threadIdx.x;  // 0..2097151
  const int g = tid & 31;                          // j-quad (j = 4g..4g+3)
  const int i = (tid >> 5) & 127;
  const int o = (tid >> 12) & 63;
  const int b = tid >> 18;

  float ys = fmaxf(0.5f * (float)i - 0.25f, 0.f);
  int   y0 = (int)ys;
  float wy = ys - (float)y0;
  int   y1 = min(y0 + 1, 63);

  const u32* Yw = (const u32*)(Ya + ((size_t)(b * 64 + o)) * 4096);
  const int base0 = y0 * 32, base1 = y1 * 32;
  const int gm = (g == 0) ? 0 : g - 1;
  const int gp = (g == 31) ? 31 : g + 1;

  u32 tm = Yw[base0 + gm], t0 = Yw[base0 + g], tp = Yw[base0 + gp];
  u32 bm = Yw[base1 + gm], b0w = Yw[base1 + g], bp = Yw[base1 + gp];

  const float iw = 1.f - wy;
  // row-interpolated values at x = 2g-1, 2g, 2g+1, 2g+2
  float r_m1 = iw * bfhi(tm) + wy * bfhi(bm);
  float r_0  = iw * bflo(t0) + wy * bflo(b0w);
  float r_1  = iw * bfhi(t0) + wy * bfhi(b0w);
  float r_2  = iw * bflo(tp) + wy * bflo(bp);

  float v0 = (g == 0)  ? r_0 : 0.25f * r_m1 + 0.75f * r_0;
  float v1 = 0.75f * r_0 + 0.25f * r_1;
  float v2 = 0.25f * r_0 + 0.75f * r_1;
  float v3 = (g == 31) ? r_1 : 0.75f * r_1 + 0.25f * r_2;

  v0 = (v0 >= 0.f) ? v0 : 0.2f * v0;
  v1 = (v1 >= 0.f) ? v1 : 0.2f * v1;
  v2 = (v2 >= 0.f) ? v2 : 0.2f * v2;
  v3 = (v3 >= 0.f) ? v3 : 0.2f * v3;

  const size_t pix = ((size_t)((b * 64 + o) * 128 + i)) * 128 + g * 4;
  float4 rv = *(const float4*)(rgb + pix);
  float4 ov;
  ov.x = rv.x + v0;
  ov.y = rv.y + v1;
  ov.z = rv.z + v2;
  ov.w = rv.w + v3;
  *(float4*)(out + pix) = ov;
}

// ---------------------------------------------------------------------------
extern "C" void kernel_launch(void* const* d_in, const int* in_sizes, int n_in,
                              void* d_out, int out_size, void* d_ws, size_t ws_size,
                              hipStream_t stream) {
  (void)in_sizes; (void)n_in; (void)out_size; (void)ws_size;
  const float* rgb  = (const float*)d_in[0];
  const float* freq = (const float*)d_in[1];
  const float* wq   = (const float*)d_in[2];
  const float* bq   = (const float*)d_in[3];
  const float* wk   = (const float*)d_in[4];
  const float* bk   = (const float*)d_in[5];
  const float* wv   = (const float*)d_in[6];
  const float* bv   = (const float*)d_in[7];
  const float* wo   = (const float*)d_in[8];
  const float* bo   = (const float*)d_in[9];
  const float* gam  = (const float*)d_in[10];
  const float* bet  = (const float*)d_in[11];
  const float* mean = (const float*)d_in[12];
  const float* var  = (const float*)d_in[13];

  char* ws = (char*)d_ws;
  u16* Qw = (u16*)(ws);               // 8*4096*64 bf16 = 4 MiB
  u16* Kw = (u16*)(ws + 4194304);     // 4 MiB
  u16* Vw = (u16*)(ws + 8388608);     // 4 MiB (transposed [b][c][n])
  u16* Yw = (u16*)(ws + 12582912);    // 4 MiB  Ya[b][64 o][4096 n] (ch-outer)

  k_qkv<<<dim3(1024), dim3(256), 0, stream>>>(rgb, freq, wq, bq, wk, bk, wv, bv,
                                              Qw, Kw, Vw);
  k_attn<<<dim3(8, 64), dim3(256), 0, stream>>>(Qw, Kw, Vw, wo, bo, gam, bet,
                                                mean, var, Yw);
  k_out<<<dim3(8192), dim3(256), 0, stream>>>(Yw, rgb, (float*)d_out);
}